// Round 2
// baseline (15642.328 us; speedup 1.0000x reference)
//
#include <hip/hip_runtime.h>
#include <hip/hip_bf16.h>
#include <stdint.h>

// Problem constants (from reference)
#define T_TOK 4096
#define D_DIM 512
#define L_SPAN 10
#define H_DIM 512
#define N_SPAN 40960
#define K_TOP 1638  // int(0.4 * 4096)

// ---------------------------------------------------------------------------
// Generic fp32 GEMM: C = act(A[M x K] @ B[K x N] + bias), row-major.
// BM=BN=128, BK=32, 256 threads, 8x8 micro-tile per thread.
// Register-prefetch of the next K-tile overlaps global loads with FMAs.
// A loads are float2 (g rows start at float offset 1638 -> only 8B aligned).
// M % 128 == 0, N % 128 == 0, K % 32 == 0 hold for every call here.
// ---------------------------------------------------------------------------
template <bool RELU>
__global__ __launch_bounds__(256, 2) void sgemm_bias(
    const float* __restrict__ A, const float* __restrict__ B,
    const float* __restrict__ bias, float* __restrict__ C,
    int M, int Nn, int Kk, int lda, int ldb, int ldc) {
  const int BM = 128, BN = 128, BK = 32;
  __shared__ float As[BK][BM + 4];  // transposed: As[k][m]; stride 132 (16B-aligned rows)
  __shared__ float Bs[BK][BN + 8];  // Bs[k][n]; stride 136 (16B-aligned rows)

  int tid = threadIdx.x;
  int bn = blockIdx.x, bm = blockIdx.y;
  int tx = tid & 15, ty = tid >> 4;

  const float* Ab = A + (size_t)bm * BM * lda;
  const float* Bb = B + (size_t)bn * BN;

  float acc[8][8];
#pragma unroll
  for (int i = 0; i < 8; ++i)
#pragma unroll
    for (int j = 0; j < 8; ++j) acc[i][j] = 0.f;

  // Staging decomposition (256 threads):
  //   A tile 128x32: a_k2 = float2 index over k (16*2=32), a_m row, 8 passes of 16 rows.
  //   B tile 32x128: b_c4 = float4 index over n (32*4=128), b_kr k-row, 4 passes of 8 rows.
  int a_k2 = tid & 15;
  int a_m = tid >> 4;
  int b_c4 = tid & 31;
  int b_kr = tid >> 5;

  float2 pa[8];
  float4 pb[4];

  auto load_tile = [&](int k0) {
#pragma unroll
    for (int p = 0; p < 8; ++p)
      pa[p] = *(const float2*)(Ab + (size_t)(a_m + p * 16) * lda + k0 + a_k2 * 2);
#pragma unroll
    for (int p = 0; p < 4; ++p)
      pb[p] = *(const float4*)(Bb + (size_t)(k0 + b_kr + p * 8) * ldb + b_c4 * 4);
  };
  auto store_tile = [&]() {
#pragma unroll
    for (int p = 0; p < 8; ++p) {
      As[a_k2 * 2 + 0][a_m + p * 16] = pa[p].x;
      As[a_k2 * 2 + 1][a_m + p * 16] = pa[p].y;
    }
#pragma unroll
    for (int p = 0; p < 4; ++p) *(float4*)&Bs[b_kr + p * 8][b_c4 * 4] = pb[p];
  };

  load_tile(0);
  store_tile();
  __syncthreads();

  for (int k0 = 0; k0 < Kk; k0 += BK) {
    bool more = (k0 + BK) < Kk;
    if (more) load_tile(k0 + BK);  // prefetch next tile into registers

#pragma unroll
    for (int kk = 0; kk < BK; ++kk) {
      float4 a0 = *(const float4*)&As[kk][ty * 8];
      float4 a1 = *(const float4*)&As[kk][ty * 8 + 4];
      float4 b0 = *(const float4*)&Bs[kk][tx * 8];
      float4 b1 = *(const float4*)&Bs[kk][tx * 8 + 4];
      float av[8] = {a0.x, a0.y, a0.z, a0.w, a1.x, a1.y, a1.z, a1.w};
      float bv[8] = {b0.x, b0.y, b0.z, b0.w, b1.x, b1.y, b1.z, b1.w};
#pragma unroll
      for (int i = 0; i < 8; ++i)
#pragma unroll
        for (int j = 0; j < 8; ++j) acc[i][j] = fmaf(av[i], bv[j], acc[i][j]);
    }
    __syncthreads();
    if (more) {
      store_tile();
    }
    __syncthreads();
  }

  int col0 = bn * BN + tx * 8;
  float bb[8];
#pragma unroll
  for (int j = 0; j < 8; ++j) bb[j] = bias[col0 + j];
#pragma unroll
  for (int i = 0; i < 8; ++i) {
    int row = bm * BM + ty * 8 + i;
    float o[8];
#pragma unroll
    for (int j = 0; j < 8; ++j) {
      float v = acc[i][j] + bb[j];
      o[j] = RELU ? fmaxf(v, 0.f) : v;
    }
    *(float4*)(C + (size_t)row * ldc + col0) = make_float4(o[0], o[1], o[2], o[3]);
    *(float4*)(C + (size_t)row * ldc + col0 + 4) = make_float4(o[4], o[5], o[6], o[7]);
  }
}

// ---------------------------------------------------------------------------
// Row dot: out[r] = dot(X[r, 0:512], w) + b[0]. One wave (64 lanes) per row.
// ---------------------------------------------------------------------------
__global__ __launch_bounds__(256) void rowdot_kernel(
    const float* __restrict__ X, const float* __restrict__ w,
    const float* __restrict__ b, float* __restrict__ out, int rows) {
  int gid = blockIdx.x * blockDim.x + threadIdx.x;
  int wave = gid >> 6;
  int lane = threadIdx.x & 63;
  if (wave >= rows) return;
  const float* x = X + (size_t)wave * H_DIM;
  float s = 0.f;
#pragma unroll
  for (int i = 0; i < 8; ++i) s = fmaf(x[lane + i * 64], w[lane + i * 64], s);
#pragma unroll
  for (int off = 32; off > 0; off >>= 1) s += __shfl_down(s, off);
  if (lane == 0) out[wave] = s + b[0];
}

// ---------------------------------------------------------------------------
// Span kernel: per span, masked softmax over attention logits, weighted sum
// of embeds, and assembly of g = [states[start], states[end], attended].
// g is written straight into d_out (base is only 8B-aligned -> float2).
// ---------------------------------------------------------------------------
__global__ __launch_bounds__(256) void span_kernel(
    const float* __restrict__ states, const float* __restrict__ embeds,
    const int* __restrict__ starts, const int* __restrict__ widths,
    const float* __restrict__ attns, float* __restrict__ g) {
  int n = blockIdx.x;
  int tid = threadIdx.x;
  int st = starts[n];
  int wd = widths[n];

  // Softmax weights over the (wd+1) valid positions, redundantly per thread.
  float w[L_SPAN];
  float mx = -1e30f;
  for (int l = 0; l <= wd; ++l) {
    float a = attns[st + l];
    w[l] = a;
    mx = fmaxf(mx, a);
  }
  float ssum = 0.f;
  for (int l = 0; l <= wd; ++l) {
    float e = expf(w[l] - mx);
    w[l] = e;
    ssum += e;
  }
  float inv = 1.f / ssum;

  int d = tid * 2;  // 256 threads x 2 cols = 512
  float2 att = make_float2(0.f, 0.f);
  for (int l = 0; l <= wd; ++l) {
    float2 e = *(const float2*)(embeds + (size_t)(st + l) * D_DIM + d);
    float wl = w[l] * inv;
    att.x = fmaf(wl, e.x, att.x);
    att.y = fmaf(wl, e.y, att.y);
  }

  float* grow = g + (size_t)n * (3 * D_DIM);
  float2 s0 = *(const float2*)(states + (size_t)st * D_DIM + d);
  float2 s1 = *(const float2*)(states + (size_t)(st + wd) * D_DIM + d);
  *(float2*)(grow + d) = s0;
  *(float2*)(grow + D_DIM + d) = s1;
  *(float2*)(grow + 2 * D_DIM + d) = att;
}

// ---------------------------------------------------------------------------
// Top-k machinery: orderable keys, 2-level 16-bit radix select, stable
// tie-break (lowest index first, matching jax.lax.top_k), bitonic index sort.
// meta: 0:b1 1:rem1 2:thr 3:need_eq 4:cntGT 5:cntEQ
// ---------------------------------------------------------------------------
__global__ void keys_kernel(const float* __restrict__ scores, uint32_t* __restrict__ keys) {
  int n = blockIdx.x * blockDim.x + threadIdx.x;
  if (n < N_SPAN) {
    uint32_t u = __float_as_uint(scores[n]);
    keys[n] = (u & 0x80000000u) ? ~u : (u | 0x80000000u);
  }
}

__global__ void zero_kernel(uint32_t* __restrict__ p, int n) {
  int i = blockIdx.x * blockDim.x + threadIdx.x;
  if (i < n) p[i] = 0u;
}

__global__ void hist_hi_kernel(const uint32_t* __restrict__ keys, uint32_t* __restrict__ hist) {
  int n = blockIdx.x * blockDim.x + threadIdx.x;
  if (n < N_SPAN) atomicAdd(&hist[keys[n] >> 16], 1u);
}

__global__ void hist_lo_kernel(const uint32_t* __restrict__ keys,
                               const uint32_t* __restrict__ meta,
                               uint32_t* __restrict__ hist) {
  int n = blockIdx.x * blockDim.x + threadIdx.x;
  if (n < N_SPAN) {
    uint32_t k = keys[n];
    if ((k >> 16) == meta[0]) atomicAdd(&hist[k & 0xffffu], 1u);
  }
}

__global__ __launch_bounds__(1024) void select_kernel(
    const uint32_t* __restrict__ hist, uint32_t* __restrict__ meta, int level) {
  __shared__ uint32_t csum[1024];
  int tid = threadIdx.x;
  uint32_t Kwant = (level == 0) ? (uint32_t)K_TOP : meta[1];

  uint32_t s = 0;
  for (int j = 0; j < 64; ++j) s += hist[tid * 64 + j];
  csum[tid] = s;
  __syncthreads();
  // inclusive suffix scan (Hillis-Steele)
  for (int off = 1; off < 1024; off <<= 1) {
    uint32_t other = (tid + off < 1024) ? csum[tid + off] : 0u;
    __syncthreads();
    csum[tid] += other;
    __syncthreads();
  }
  // the unique chunk where the Kwant-th largest lands
  if (csum[tid] >= Kwant && (tid == 1023 || csum[tid + 1] < Kwant)) {
    uint32_t running = (tid == 1023) ? 0u : csum[tid + 1];
    for (int j = 63; j >= 0; --j) {
      uint32_t h = hist[tid * 64 + j];
      if (running + h >= Kwant) {
        if (level == 0) {
          meta[0] = (uint32_t)(tid * 64 + j);
          meta[1] = Kwant - running;
        } else {
          meta[2] = (meta[0] << 16) | (uint32_t)(tid * 64 + j);
          meta[3] = Kwant - running;
        }
        break;
      }
      running += h;
    }
  }
}

__global__ void compact_kernel(const uint32_t* __restrict__ keys, uint32_t* __restrict__ meta,
                               int* __restrict__ selGT, int* __restrict__ selEQ) {
  int n = blockIdx.x * blockDim.x + threadIdx.x;
  if (n >= N_SPAN) return;
  uint32_t k = keys[n];
  uint32_t thr = meta[2];
  if (k > thr) {
    uint32_t p = atomicAdd(&meta[4], 1u);
    selGT[p] = n;
  } else if (k == thr) {
    uint32_t p = atomicAdd(&meta[5], 1u);
    selEQ[p] = n;
  }
}

__global__ __launch_bounds__(1024) void final_kernel(
    const uint32_t* __restrict__ meta, const int* __restrict__ selGT,
    const int* __restrict__ selEQ, const float* __restrict__ scores,
    float* __restrict__ out_scores, float* __restrict__ out_idx) {
  __shared__ int sel[2048];
  int tid = threadIdx.x;
  int cnt_gt = (int)meta[4];
  int cnt_eq = (int)meta[5];
  int need_eq = (int)meta[3];

  for (int i = tid; i < 2048; i += 1024) sel[i] = 0x7fffffff;
  __syncthreads();
  for (int i = tid; i < cnt_gt; i += 1024) sel[i] = selGT[i];
  // stable tie-break: among threshold-equal scores, keep lowest indices
  for (int i = tid; i < cnt_eq; i += 1024) {
    int idx = selEQ[i];
    int rank = 0;
    for (int j = 0; j < cnt_eq; ++j) rank += (selEQ[j] < idx) ? 1 : 0;
    if (rank < need_eq) sel[cnt_gt + rank] = idx;
  }
  __syncthreads();
  // bitonic ascending sort of 2048 ints
  for (int kk = 2; kk <= 2048; kk <<= 1) {
    for (int j = kk >> 1; j > 0; j >>= 1) {
      for (int t = tid; t < 2048; t += 1024) {
        int ixj = t ^ j;
        if (ixj > t) {
          bool up = ((t & kk) == 0);
          int a = sel[t], b = sel[ixj];
          if ((a > b) == up) {
            sel[t] = b;
            sel[ixj] = a;
          }
        }
      }
      __syncthreads();
    }
  }
  for (int i = tid; i < K_TOP; i += 1024) {
    int idx = sel[i];
    out_scores[i] = scores[idx];
    out_idx[i] = (float)idx;
  }
}

// ---------------------------------------------------------------------------
extern "C" void kernel_launch(void* const* d_in, const int* in_sizes, int n_in,
                              void* d_out, int out_size, void* d_ws, size_t ws_size,
                              hipStream_t stream) {
  const float* states = (const float*)d_in[0];
  const float* embeds = (const float*)d_in[1];
  const int* starts = (const int*)d_in[2];
  const int* widths = (const int*)d_in[3];
  const float* W_a1 = (const float*)d_in[4];
  const float* b_a1 = (const float*)d_in[5];
  const float* W_a2 = (const float*)d_in[6];
  const float* b_a2 = (const float*)d_in[7];
  const float* w_a3 = (const float*)d_in[8];
  const float* b_a3 = (const float*)d_in[9];
  const float* W_s1 = (const float*)d_in[10];
  const float* b_s1 = (const float*)d_in[11];
  const float* W_s2 = (const float*)d_in[12];
  const float* b_s2 = (const float*)d_in[13];
  const float* w_s3 = (const float*)d_in[14];
  const float* b_s3 = (const float*)d_in[15];

  float* out = (float*)d_out;
  float* out_scores = out;                                    // [0, 1638)
  float* g = out + K_TOP;                                     // [1638, +N*3D)
  float* out_idx = out + K_TOP + (size_t)N_SPAN * 3 * D_DIM;  // final 1638

  // Workspace carve-up with lifetime-based overlap. Total need = 2*REG.
  //   region A (REG): s1  -> (after GEMM2 consumed s1) scores/keys/hist/meta/sel
  //   region B (REG): h1 | h2 | attns -> (after span_kernel) s2
  char* wsA = (char*)d_ws;
  const size_t REG = (size_t)N_SPAN * H_DIM * sizeof(float);  // 83.9 MB
  char* wsB = wsA + REG;

  float* s1w = (float*)wsA;
  float* h1 = (float*)wsB;                                       // 8 MB (T*H*4)
  float* h2 = (float*)(wsB + (size_t)T_TOK * H_DIM * 4);         // 8 MB
  float* attns = (float*)(wsB + 2 * (size_t)T_TOK * H_DIM * 4);  // 16 KB
  float* s2w = (float*)wsB;                                      // overwrites h1/h2/attns

  char* p = wsA;  // s1 is dead once GEMM2 has read it
  float* scores = (float*)p;     p += (size_t)N_SPAN * sizeof(float);
  uint32_t* keys = (uint32_t*)p; p += (size_t)N_SPAN * sizeof(uint32_t);
  uint32_t* hist = (uint32_t*)p; p += 65536 * sizeof(uint32_t);
  uint32_t* meta = (uint32_t*)p; p += 16 * sizeof(uint32_t);
  int* selGT = (int*)p;          p += (size_t)N_SPAN * sizeof(int);
  int* selEQ = (int*)p;          p += (size_t)N_SPAN * sizeof(int);

  // 1-2: attention MLP hidden layers
  sgemm_bias<true><<<dim3(H_DIM / 128, T_TOK / 128), 256, 0, stream>>>(
      states, W_a1, b_a1, h1, T_TOK, H_DIM, D_DIM, D_DIM, H_DIM, H_DIM);
  sgemm_bias<true><<<dim3(H_DIM / 128, T_TOK / 128), 256, 0, stream>>>(
      h1, W_a2, b_a2, h2, T_TOK, H_DIM, H_DIM, H_DIM, H_DIM, H_DIM);
  // 3: attention logits
  rowdot_kernel<<<T_TOK / 4, 256, 0, stream>>>(h2, w_a3, b_a3, attns, T_TOK);
  // 4: span softmax + attended + g assembly (writes g into d_out)
  span_kernel<<<N_SPAN, 256, 0, stream>>>(states, embeds, starts, widths, attns, g);
  // 5-6: mention MLP hidden layers
  sgemm_bias<true><<<dim3(H_DIM / 128, N_SPAN / 128), 256, 0, stream>>>(
      g, W_s1, b_s1, s1w, N_SPAN, H_DIM, 3 * D_DIM, 3 * D_DIM, H_DIM, H_DIM);
  sgemm_bias<true><<<dim3(H_DIM / 128, N_SPAN / 128), 256, 0, stream>>>(
      s1w, W_s2, b_s2, s2w, N_SPAN, H_DIM, H_DIM, H_DIM, H_DIM, H_DIM);
  // 7: mention scores (s1 region becomes free here; scores lives there)
  rowdot_kernel<<<N_SPAN / 4, 256, 0, stream>>>(s2w, w_s3, b_s3, scores, N_SPAN);

  // 8-16: top-k (k=1638) + stable tie-break + sorted indices + output
  keys_kernel<<<N_SPAN / 256, 256, 0, stream>>>(scores, keys);
  zero_kernel<<<(65536 + 16 + 255) / 256, 256, 0, stream>>>(hist, 65536 + 16);
  hist_hi_kernel<<<N_SPAN / 256, 256, 0, stream>>>(keys, hist);
  select_kernel<<<1, 1024, 0, stream>>>(hist, meta, 0);
  zero_kernel<<<65536 / 256, 256, 0, stream>>>(hist, 65536);
  hist_lo_kernel<<<N_SPAN / 256, 256, 0, stream>>>(keys, meta, hist);
  select_kernel<<<1, 1024, 0, stream>>>(hist, meta, 1);
  compact_kernel<<<N_SPAN / 256, 256, 0, stream>>>(keys, meta, selGT, selEQ);
  final_kernel<<<1, 1024, 0, stream>>>(meta, selGT, selEQ, scores, out_scores, out_idx);
}

// Round 5
// 1482.232 us; speedup vs baseline: 10.5532x; 10.5532x over previous
//
#include <hip/hip_runtime.h>
#include <hip/hip_bf16.h>
#include <stdint.h>

// Problem constants (from reference)
#define T_TOK 4096
#define D_DIM 512
#define L_SPAN 10
#define H_DIM 512
#define N_SPAN 40960
#define K_TOP 1638      // int(0.4 * 4096)
#define CAND_CAP 6144   // candidate capacity for exact re-score
#define MARGIN 0.01f    // approx-score margin (bf16-path err ~0.002)

typedef __attribute__((ext_vector_type(8))) short bf16x8;
typedef __attribute__((ext_vector_type(4))) float f32x4;

__device__ __forceinline__ ushort f2bf(float x) {  // RNE float->bf16 bits
  uint32_t u = __float_as_uint(x);
  return (ushort)((u + 0x7FFFu + ((u >> 16) & 1u)) >> 16);
}
__device__ __forceinline__ float bf2f(ushort s) {
  return __uint_as_float(((uint32_t)s) << 16);
}

// ---------------------------------------------------------------------------
// fp32 GEMM (R2-validated numeric order): C = relu(A@B + bias). BM=BN=128,
// BK=16, 256 thr, 8x8 micro-tile. Per-element dot accumulates in pure
// ascending-k order -> bitwise identical results for any tiling of rows.
// ---------------------------------------------------------------------------
template <bool RELU>
__global__ __launch_bounds__(256) void sgemm_bias(
    const float* __restrict__ A, const float* __restrict__ B,
    const float* __restrict__ bias, float* __restrict__ C,
    int M, int Nn, int Kk, int lda, int ldb, int ldc) {
  const int BM = 128, BN = 128, BK = 16;
  __shared__ float As[BK][BM + 4];
  __shared__ float Bs[BK][BN + 8];

  int tid = threadIdx.x;
  int bm = blockIdx.x, bn = blockIdx.y;
  int tx = tid & 15, ty = tid >> 4;

  int a_k2 = tid & 7;
  int a_m = tid >> 3;
  int b_c4 = tid & 31;
  int b_kr = tid >> 5;

  const float* aPtr = A + (size_t)(bm * BM + a_m) * lda + a_k2 * 2;
  const float* bPtr = B + (size_t)b_kr * ldb + (size_t)bn * BN + b_c4 * 4;

  float acc[8][8];
#pragma unroll
  for (int i = 0; i < 8; ++i)
#pragma unroll
    for (int j = 0; j < 8; ++j) acc[i][j] = 0.f;

  for (int k0 = 0; k0 < Kk; k0 += BK) {
#pragma unroll
    for (int p = 0; p < 4; ++p) {
      float2 v = *(const float2*)(aPtr + (size_t)p * 32 * lda);
      As[a_k2 * 2 + 0][a_m + p * 32] = v.x;
      As[a_k2 * 2 + 1][a_m + p * 32] = v.y;
    }
#pragma unroll
    for (int p = 0; p < 2; ++p) {
      float4 v = *(const float4*)(bPtr + (size_t)p * 8 * ldb);
      *(float4*)&Bs[b_kr + p * 8][b_c4 * 4] = v;
    }
    aPtr += BK;
    bPtr += (size_t)BK * ldb;
    __syncthreads();

#pragma unroll
    for (int kk = 0; kk < BK; ++kk) {
      float4 a0 = *(const float4*)&As[kk][ty * 8];
      float4 a1 = *(const float4*)&As[kk][ty * 8 + 4];
      float4 b0 = *(const float4*)&Bs[kk][tx * 8];
      float4 b1 = *(const float4*)&Bs[kk][tx * 8 + 4];
#pragma unroll
      for (int i = 0; i < 8; ++i) {
        float ai = (i < 4) ? ((i == 0) ? a0.x : (i == 1) ? a0.y : (i == 2) ? a0.z : a0.w)
                           : ((i == 4) ? a1.x : (i == 5) ? a1.y : (i == 6) ? a1.z : a1.w);
        acc[i][0] = fmaf(ai, b0.x, acc[i][0]);
        acc[i][1] = fmaf(ai, b0.y, acc[i][1]);
        acc[i][2] = fmaf(ai, b0.z, acc[i][2]);
        acc[i][3] = fmaf(ai, b0.w, acc[i][3]);
        acc[i][4] = fmaf(ai, b1.x, acc[i][4]);
        acc[i][5] = fmaf(ai, b1.y, acc[i][5]);
        acc[i][6] = fmaf(ai, b1.z, acc[i][6]);
        acc[i][7] = fmaf(ai, b1.w, acc[i][7]);
      }
    }
    __syncthreads();
  }

  int col0 = bn * BN + tx * 8;
  float bb[8];
#pragma unroll
  for (int j = 0; j < 8; ++j) bb[j] = bias[col0 + j];
#pragma unroll
  for (int i = 0; i < 8; ++i) {
    int row = bm * BM + ty * 8 + i;
    float o[8];
#pragma unroll
    for (int j = 0; j < 8; ++j) {
      float v = acc[i][j] + bb[j];
      o[j] = RELU ? fmaxf(v, 0.f) : v;
    }
    *(float4*)(C + (size_t)row * ldc + col0) = make_float4(o[0], o[1], o[2], o[3]);
    *(float4*)(C + (size_t)row * ldc + col0 + 4) = make_float4(o[4], o[5], o[6], o[7]);
  }
}

// ---------------------------------------------------------------------------
// bf16 MFMA GEMM: Out_bf16 = relu(A @ B_bf16 + bias). 16x16x32 MFMA.
// Block 256 thr = 4 waves (2x2), tile 128x64, BK=32. A is fp32 (converted in
// staging, AF32=true) or bf16 (AF32=false). N fixed at 512, M = 320*128.
// Grid 2560 1-D: wg = bn*320 + p so all 8 n-blocks of row-panel p share
// wg%8 (same XCD L2 -> A panel fetched ~once per XCD).
// Frag layouts (16x16x32): A row=l&15, k=(l>>4)*8+j ; B col=l&15, same k;
// C/D col=l&15, row=(l>>4)*4+r  [guide-verified m89].
// ---------------------------------------------------------------------------
template <bool AF32>
__global__ __launch_bounds__(256) void mfma_gemm(
    const void* __restrict__ Aptr, const ushort* __restrict__ Bb,
    const float* __restrict__ bias, ushort* __restrict__ Out,
    int K, int lda) {
  __shared__ ushort As[128][48];  // row stride 96B: 16B-aligned, 4-way-bank at worst
  __shared__ ushort Bs[64][48];   // transposed: Bs[n][k]

  int wg = blockIdx.x;
  int bn = wg / 320;
  int p = wg % 320;
  int tid = threadIdx.x;
  int w = tid >> 6, l = tid & 63;
  int waveM = w & 1, waveN = w >> 1;
  int lr = l & 15, lg = l >> 4;
  int rowbase = p * 128;

  f32x4 acc[4][2];
#pragma unroll
  for (int m = 0; m < 4; ++m)
#pragma unroll
    for (int n = 0; n < 2; ++n)
#pragma unroll
      for (int r = 0; r < 4; ++r) acc[m][n][r] = 0.f;

  const float* Af = (const float*)Aptr;
  const ushort* Ab = (const ushort*)Aptr;

  for (int k0 = 0; k0 < K; k0 += 32) {
    // stage A tile 128x32
#pragma unroll
    for (int it = 0; it < 2; ++it) {
      int idx = tid + it * 256;  // 0..511
      int ar = idx >> 2;
      int kc = (idx & 3) * 8;
      if (AF32) {
        const float* s = Af + (size_t)(rowbase + ar) * lda + k0 + kc;
        float2 v0 = *(const float2*)(s);
        float2 v1 = *(const float2*)(s + 2);
        float2 v2 = *(const float2*)(s + 4);
        float2 v3 = *(const float2*)(s + 6);
        ushort* d = &As[ar][kc];
        d[0] = f2bf(v0.x); d[1] = f2bf(v0.y);
        d[2] = f2bf(v1.x); d[3] = f2bf(v1.y);
        d[4] = f2bf(v2.x); d[5] = f2bf(v2.y);
        d[6] = f2bf(v3.x); d[7] = f2bf(v3.y);
      } else {
        const ushort* s = Ab + (size_t)(rowbase + ar) * lda + k0 + kc;
        *(uint4*)&As[ar][kc] = *(const uint4*)s;
      }
    }
    // stage B tile 32x64, transposed into Bs[n][k]
    {
      int n = tid & 63;
      int kk0 = (tid >> 6) * 8;
#pragma unroll
      for (int i = 0; i < 8; ++i)
        Bs[n][kk0 + i] = Bb[(size_t)(k0 + kk0 + i) * 512 + bn * 64 + n];
    }
    __syncthreads();

    bf16x8 af[4], bv[2];
#pragma unroll
    for (int m = 0; m < 4; ++m)
      af[m] = *(const bf16x8*)&As[waveM * 64 + m * 16 + lr][lg * 8];
#pragma unroll
    for (int n = 0; n < 2; ++n)
      bv[n] = *(const bf16x8*)&Bs[waveN * 32 + n * 16 + lr][lg * 8];
#pragma unroll
    for (int m = 0; m < 4; ++m)
#pragma unroll
      for (int n = 0; n < 2; ++n)
        acc[m][n] = __builtin_amdgcn_mfma_f32_16x16x32_bf16(af[m], bv[n], acc[m][n], 0, 0, 0);
    __syncthreads();
  }

#pragma unroll
  for (int m = 0; m < 4; ++m) {
    int rg = rowbase + waveM * 64 + m * 16 + lg * 4;
#pragma unroll
    for (int n = 0; n < 2; ++n) {
      int cg = bn * 64 + waveN * 32 + n * 16 + lr;
      float bb = bias[cg];
#pragma unroll
      for (int r = 0; r < 4; ++r) {
        float v = fmaxf(acc[m][n][r] + bb, 0.f);
        Out[(size_t)(rg + r) * 512 + cg] = f2bf(v);
      }
    }
  }
}

// ---------------------------------------------------------------------------
__global__ void cvt_bf16_kernel(const float* __restrict__ src, ushort* __restrict__ dst, int n) {
  int i = blockIdx.x * blockDim.x + threadIdx.x;
  if (i < n) dst[i] = f2bf(src[i]);
}

// Row dot fp32: out[r] = dot(X[r,0:512], w) + b[0]. One wave per row.
__global__ __launch_bounds__(256) void rowdot_kernel(
    const float* __restrict__ X, const float* __restrict__ w,
    const float* __restrict__ b, float* __restrict__ out, int rows) {
  int gid = blockIdx.x * blockDim.x + threadIdx.x;
  int wave = gid >> 6;
  int lane = threadIdx.x & 63;
  if (wave >= rows) return;
  const float* x = X + (size_t)wave * H_DIM;
  float s = 0.f;
#pragma unroll
  for (int i = 0; i < 8; ++i) s = fmaf(x[lane + i * 64], w[lane + i * 64], s);
#pragma unroll
  for (int off = 32; off > 0; off >>= 1) s += __shfl_down(s, off);
  if (lane == 0) out[wave] = s + b[0];
}

// Row dot bf16 input (approx path).
__global__ __launch_bounds__(256) void rowdot_bf16_kernel(
    const ushort* __restrict__ X, const float* __restrict__ w,
    const float* __restrict__ b, float* __restrict__ out, int rows) {
  int gid = blockIdx.x * blockDim.x + threadIdx.x;
  int wave = gid >> 6;
  int lane = threadIdx.x & 63;
  if (wave >= rows) return;
  const ushort* x = X + (size_t)wave * H_DIM;
  float s = 0.f;
#pragma unroll
  for (int i = 0; i < 8; ++i) s = fmaf(bf2f(x[lane + i * 64]), w[lane + i * 64], s);
#pragma unroll
  for (int off = 32; off > 0; off >>= 1) s += __shfl_down(s, off);
  if (lane == 0) out[wave] = s + b[0];
}

// ---------------------------------------------------------------------------
// Span kernel (bit-matches R2-validated path: expf, same accumulation).
// ---------------------------------------------------------------------------
__global__ __launch_bounds__(256) void span_kernel(
    const float* __restrict__ states, const float* __restrict__ embeds,
    const int* __restrict__ starts, const int* __restrict__ widths,
    const float* __restrict__ attns, float* __restrict__ g) {
  int n = blockIdx.x;
  int tid = threadIdx.x;
  int st = starts[n];
  int wd = widths[n];

  float w[L_SPAN];
  float mx = -1e30f;
#pragma unroll
  for (int l = 0; l < L_SPAN; ++l) {
    float a = attns[st + l];  // in-range: st+9 <= T-1
    a = (l <= wd) ? a : -1e30f;
    w[l] = a;
    mx = fmaxf(mx, a);
  }
  float ssum = 0.f;
#pragma unroll
  for (int l = 0; l < L_SPAN; ++l) {
    float e = expf(w[l] - mx);
    e = (l <= wd) ? e : 0.f;
    w[l] = e;
    ssum += e;
  }
  float inv = 1.f / ssum;

  int d = tid * 2;
  float2 att = make_float2(0.f, 0.f);
#pragma unroll
  for (int l = 0; l < L_SPAN; ++l) {
    float2 e = *(const float2*)(embeds + (size_t)(st + l) * D_DIM + d);
    float wl = w[l] * inv;
    att.x = fmaf(wl, e.x, att.x);
    att.y = fmaf(wl, e.y, att.y);
  }

  float* grow = g + (size_t)n * (3 * D_DIM);
  float2 s0 = *(const float2*)(states + (size_t)st * D_DIM + d);
  float2 s1 = *(const float2*)(states + (size_t)(st + wd) * D_DIM + d);
  *(float2*)(grow + d) = s0;
  *(float2*)(grow + D_DIM + d) = s1;
  *(float2*)(grow + 2 * D_DIM + d) = att;
}

// ---------------------------------------------------------------------------
// Radix-select machinery on approx scores.
// meta: 0:b1 1:rem1 2:thr_key 3:need_eq 4,5:unused 6:candCount
// ---------------------------------------------------------------------------
__global__ void keys_kernel(const float* __restrict__ scores, uint32_t* __restrict__ keys) {
  int n = blockIdx.x * blockDim.x + threadIdx.x;
  if (n < N_SPAN) {
    uint32_t u = __float_as_uint(scores[n]);
    keys[n] = (u & 0x80000000u) ? ~u : (u | 0x80000000u);
  }
}

__global__ void zero_kernel(uint32_t* __restrict__ p, int n) {
  int i = blockIdx.x * blockDim.x + threadIdx.x;
  if (i < n) p[i] = 0u;
}

__global__ void hist_hi_kernel(const uint32_t* __restrict__ keys, uint32_t* __restrict__ hist) {
  int n = blockIdx.x * blockDim.x + threadIdx.x;
  if (n < N_SPAN) atomicAdd(&hist[keys[n] >> 16], 1u);
}

__global__ void hist_lo_kernel(const uint32_t* __restrict__ keys,
                               const uint32_t* __restrict__ meta,
                               uint32_t* __restrict__ hist) {
  int n = blockIdx.x * blockDim.x + threadIdx.x;
  if (n < N_SPAN) {
    uint32_t k = keys[n];
    if ((k >> 16) == meta[0]) atomicAdd(&hist[k & 0xffffu], 1u);
  }
}

__global__ __launch_bounds__(1024) void select_kernel(
    const uint32_t* __restrict__ hist, uint32_t* __restrict__ meta, int level) {
  __shared__ uint32_t csum[1024];
  int tid = threadIdx.x;
  uint32_t Kwant = (level == 0) ? (uint32_t)K_TOP : meta[1];

  uint32_t s = 0;
  for (int j = 0; j < 64; ++j) s += hist[tid * 64 + j];
  csum[tid] = s;
  __syncthreads();
  for (int off = 1; off < 1024; off <<= 1) {
    uint32_t other = (tid + off < 1024) ? csum[tid + off] : 0u;
    __syncthreads();
    csum[tid] += other;
    __syncthreads();
  }
  if (csum[tid] >= Kwant && (tid == 1023 || csum[tid + 1] < Kwant)) {
    uint32_t running = (tid == 1023) ? 0u : csum[tid + 1];
    for (int j = 63; j >= 0; --j) {
      uint32_t h = hist[tid * 64 + j];
      if (running + h >= Kwant) {
        if (level == 0) {
          meta[0] = (uint32_t)(tid * 64 + j);
          meta[1] = Kwant - running;
        } else {
          meta[2] = (meta[0] << 16) | (uint32_t)(tid * 64 + j);
          meta[3] = Kwant - running;
        }
        break;
      }
      running += h;
    }
  }
}

// Candidates: approx key >= key(float(thr) - MARGIN). Guarantees C >= K_TOP
// and (given |approx-exact| <= MARGIN/2) superset of the exact top-K.
__global__ void compact_cand(const uint32_t* __restrict__ keys, uint32_t* __restrict__ meta,
                             int* __restrict__ candIdx) {
  int n = blockIdx.x * blockDim.x + threadIdx.x;
  if (n >= N_SPAN) return;
  uint32_t tk = meta[2];
  uint32_t tu = (tk & 0x80000000u) ? (tk & 0x7FFFFFFFu) : ~tk;  // inverse key->bits
  float tf = __uint_as_float(tu) - MARGIN;
  uint32_t mu = __float_as_uint(tf);
  uint32_t mk = (mu & 0x80000000u) ? ~mu : (mu | 0x80000000u);
  if (keys[n] >= mk) {
    uint32_t p = atomicAdd(&meta[6], 1u);
    if (p < CAND_CAP) candIdx[p] = n;
  }
}

// Gather candidate g rows -> cand_g [CAND_CAP x 1536], zero-padded.
__global__ __launch_bounds__(256) void gather_kernel(
    const float* __restrict__ g, const uint32_t* __restrict__ meta,
    const int* __restrict__ candIdx, float* __restrict__ cand_g) {
  int r = blockIdx.x;
  int C = (int)meta[6];
  if (C > CAND_CAP) C = CAND_CAP;
  bool valid = r < C;
  int idx = valid ? candIdx[r] : 0;
  const float* srow = g + (size_t)idx * (3 * D_DIM);
  float* drow = cand_g + (size_t)r * (3 * D_DIM);
  for (int i = threadIdx.x; i < 768; i += 256) {
    float2 v = valid ? *(const float2*)(srow + i * 2) : make_float2(0.f, 0.f);
    *(float2*)(drow + i * 2) = v;
  }
}

// ---------------------------------------------------------------------------
// Final: among candidates (exact fp32 scores), top-K_TOP with stable
// tie-break (lowest index first), then sort selected by index. One block.
// ---------------------------------------------------------------------------
__global__ __launch_bounds__(1024) void final_hybrid(
    const uint32_t* __restrict__ meta, const int* __restrict__ candIdx,
    const float* __restrict__ candExact,
    float* __restrict__ out_scores, float* __restrict__ out_idx) {
  __shared__ uint64_t pr[8192];  // 64 KB
  int tid = threadIdx.x;
  int C = (int)meta[6];
  if (C > CAND_CAP) C = CAND_CAP;

  // build inverted keys: sort ASCENDING on ~((scoreKey<<32)|((0xFFFF-idx)<<13|slot))
  for (int i = tid; i < 8192; i += 1024) {
    uint64_t inv = ~0ULL;  // pad sorts last
    if (i < C) {
      uint32_t u = __float_as_uint(candExact[i]);
      uint32_t k = (u & 0x80000000u) ? ~u : (u | 0x80000000u);
      uint32_t orig = (uint32_t)candIdx[i];
      uint32_t low = ((0xFFFFu - orig) << 13) | (uint32_t)i;
      inv = ~(((uint64_t)k << 32) | low);
    }
    pr[i] = inv;
  }
  __syncthreads();
  // bitonic ascending over 8192
  for (int kk = 2; kk <= 8192; kk <<= 1) {
    for (int j = kk >> 1; j > 0; j >>= 1) {
      for (int t = tid; t < 8192; t += 1024) {
        int ixj = t ^ j;
        if (ixj > t) {
          bool up = ((t & kk) == 0);
          uint64_t a = pr[t], b = pr[ixj];
          if ((a > b) == up) { pr[t] = b; pr[ixj] = a; }
        }
      }
      __syncthreads();
    }
  }
  // ranks 0..K_TOP-1 are the selected spans; re-sort those by original index
  uint64_t mine[2];
#pragma unroll
  for (int t = 0; t < 2; ++t) {
    int i = tid + t * 1024;
    uint64_t v = ~pr[i];
    uint32_t low = (uint32_t)v;
    uint32_t orig = 0xFFFFu - ((low >> 13) & 0xFFFFu);
    uint32_t slot = low & 0x1FFFu;
    mine[t] = (i < K_TOP) ? (((uint64_t)orig << 32) | slot) : ~0ULL;
  }
  __syncthreads();
  pr[tid] = mine[0];
  pr[tid + 1024] = mine[1];
  __syncthreads();
  for (int kk = 2; kk <= 2048; kk <<= 1) {
    for (int j = kk >> 1; j > 0; j >>= 1) {
      for (int t = tid; t < 2048; t += 1024) {
        int ixj = t ^ j;
        if (ixj > t) {
          bool up = ((t & kk) == 0);
          uint64_t a = pr[t], b = pr[ixj];
          if ((a > b) == up) { pr[t] = b; pr[ixj] = a; }
        }
      }
      __syncthreads();
    }
  }
  for (int i = tid; i < K_TOP; i += 1024) {
    uint64_t v = pr[i];
    out_idx[i] = (float)(uint32_t)(v >> 32);
    out_scores[i] = candExact[v & 0x1FFFu];
  }
}

// ---------------------------------------------------------------------------
extern "C" void kernel_launch(void* const* d_in, const int* in_sizes, int n_in,
                              void* d_out, int out_size, void* d_ws, size_t ws_size,
                              hipStream_t stream) {
  const float* states = (const float*)d_in[0];
  const float* embeds = (const float*)d_in[1];
  const int* starts = (const int*)d_in[2];
  const int* widths = (const int*)d_in[3];
  const float* W_a1 = (const float*)d_in[4];
  const float* b_a1 = (const float*)d_in[5];
  const float* W_a2 = (const float*)d_in[6];
  const float* b_a2 = (const float*)d_in[7];
  const float* w_a3 = (const float*)d_in[8];
  const float* b_a3 = (const float*)d_in[9];
  const float* W_s1 = (const float*)d_in[10];
  const float* b_s1 = (const float*)d_in[11];
  const float* W_s2 = (const float*)d_in[12];
  const float* b_s2 = (const float*)d_in[13];
  const float* w_s3 = (const float*)d_in[14];
  const float* b_s3 = (const float*)d_in[15];

  float* out = (float*)d_out;
  float* out_scores = out;
  float* g = out + K_TOP;
  float* out_idx = out + K_TOP + (size_t)N_SPAN * 3 * D_DIM;

  // Workspace (<= ~164 MB; R2 proved >= 168 MB available):
  char* ws = (char*)d_ws;
  const size_t MB = 1024 * 1024;
  float* h1 = (float*)(ws + 0);             // 8 MB  (dead after rowdot attns)
  float* h2 = (float*)(ws + 8 * MB);        // 8 MB
  float* attns = (float*)(ws + 16 * MB);    // 16 KB (dead after span)
  ushort* s1b = (ushort*)(ws + 0);          // 41.9 MB (overwrites h1/h2/attns)
  ushort* s2b = (ushort*)(ws + 48 * MB);    // 41.9 MB
  ushort* Wb1 = (ushort*)(ws + 96 * MB);    // 1.5 MB
  ushort* Wb2 = (ushort*)(ws + 98 * MB);    // 0.5 MB
  float* scoresA = (float*)(ws + 99 * MB);  // 160 KB (approx scores)
  uint32_t* keys = (uint32_t*)(ws + 100 * MB);   // 160 KB
  uint32_t* hist = (uint32_t*)(ws + 101 * MB);   // 256 KB (+ meta right after)
  uint32_t* meta = hist + 65536;                 // 16 u32
  int* candIdx = (int*)(ws + 102 * MB);          // 24 KB
  float* cand_g = (float*)(ws + 103 * MB);       // 37.75 MB
  float* e1 = (float*)(ws + 141 * MB);           // 12.6 MB
  float* e2 = (float*)(ws + 154 * MB);           // 12.6 MB
  float* candExact = (float*)(ws + 167 * MB);    // 24 KB

  // 0: weights -> bf16
  cvt_bf16_kernel<<<(3 * D_DIM * H_DIM) / 256, 256, 0, stream>>>(W_s1, Wb1, 3 * D_DIM * H_DIM);
  cvt_bf16_kernel<<<(H_DIM * H_DIM) / 256, 256, 0, stream>>>(W_s2, Wb2, H_DIM * H_DIM);

  // 1-3: attention MLP (fp32, bit-matches validated path)
  sgemm_bias<true><<<dim3(T_TOK / 128, H_DIM / 128), 256, 0, stream>>>(
      states, W_a1, b_a1, h1, T_TOK, H_DIM, D_DIM, D_DIM, H_DIM, H_DIM);
  sgemm_bias<true><<<dim3(T_TOK / 128, H_DIM / 128), 256, 0, stream>>>(
      h1, W_a2, b_a2, h2, T_TOK, H_DIM, H_DIM, H_DIM, H_DIM, H_DIM);
  rowdot_kernel<<<T_TOK / 4, 256, 0, stream>>>(h2, w_a3, b_a3, attns, T_TOK);

  // 4: span softmax + g assembly (fp32, writes d_out)
  span_kernel<<<N_SPAN, 256, 0, stream>>>(states, embeds, starts, widths, attns, g);

  // 5-7: approx mention MLP via bf16 MFMA
  mfma_gemm<true><<<2560, 256, 0, stream>>>(g, Wb1, b_s1, s1b, 3 * D_DIM, 3 * D_DIM);
  mfma_gemm<false><<<2560, 256, 0, stream>>>(s1b, Wb2, b_s2, s2b, H_DIM, H_DIM);
  rowdot_bf16_kernel<<<N_SPAN / 4, 256, 0, stream>>>(s2b, w_s3, b_s3, scoresA, N_SPAN);

  // 8: approx threshold via 2-level radix select
  keys_kernel<<<N_SPAN / 256, 256, 0, stream>>>(scoresA, keys);
  zero_kernel<<<(65536 + 16 + 255) / 256, 256, 0, stream>>>(hist, 65536 + 16);
  hist_hi_kernel<<<N_SPAN / 256, 256, 0, stream>>>(keys, hist);
  select_kernel<<<1, 1024, 0, stream>>>(hist, meta, 0);
  zero_kernel<<<65536 / 256, 256, 0, stream>>>(hist, 65536);
  hist_lo_kernel<<<N_SPAN / 256, 256, 0, stream>>>(keys, meta, hist);
  select_kernel<<<1, 1024, 0, stream>>>(hist, meta, 1);

  // 9-12: candidates -> exact fp32 re-score (bitwise = validated path)
  compact_cand<<<N_SPAN / 256, 256, 0, stream>>>(keys, meta, candIdx);
  gather_kernel<<<CAND_CAP, 256, 0, stream>>>(g, meta, candIdx, cand_g);
  sgemm_bias<true><<<dim3(CAND_CAP / 128, H_DIM / 128), 256, 0, stream>>>(
      cand_g, W_s1, b_s1, e1, CAND_CAP, H_DIM, 3 * D_DIM, 3 * D_DIM, H_DIM, H_DIM);
  sgemm_bias<true><<<dim3(CAND_CAP / 128, H_DIM / 128), 256, 0, stream>>>(
      e1, W_s2, b_s2, e2, CAND_CAP, H_DIM, H_DIM, H_DIM, H_DIM, H_DIM);
  rowdot_kernel<<<CAND_CAP / 4, 256, 0, stream>>>(e2, w_s3, b_s3, candExact, CAND_CAP);

  // 13: exact top-K among candidates + index sort + output
  final_hybrid<<<1, 1024, 0, stream>>>(meta, candIdx, candExact, out_scores, out_idx);
}

// Round 7
// 1254.665 us; speedup vs baseline: 12.4673x; 1.1814x over previous
//
#include <hip/hip_runtime.h>
#include <hip/hip_bf16.h>
#include <stdint.h>

// Problem constants (from reference)
#define T_TOK 4096
#define D_DIM 512
#define L_SPAN 10
#define H_DIM 512
#define N_SPAN 40960
#define K_TOP 1638      // int(0.4 * 4096)
#define CAND_CAP 6144   // candidate capacity for exact re-score
#define MARGIN 0.01f    // approx-score margin (bf16-path err ~0.002)

typedef __attribute__((ext_vector_type(8))) short bf16x8;
typedef __attribute__((ext_vector_type(4))) float f32x4;

__device__ __forceinline__ ushort f2bf(float x) {  // RNE float->bf16 bits
  uint32_t u = __float_as_uint(x);
  return (ushort)((u + 0x7FFFu + ((u >> 16) & 1u)) >> 16);
}
__device__ __forceinline__ float bf2f(ushort s) {
  return __uint_as_float(((uint32_t)s) << 16);
}

// ---------------------------------------------------------------------------
// fp32 GEMM (R2/R4-validated numeric order): C = relu(A@B + bias). BM=BN=128,
// BK=16, 256 thr, 8x8 micro-tile. Per-element dot accumulates in pure
// ascending-k order -> bitwise identical for any row tiling. rowCnt != null:
// whole 128-row tiles beyond ceil(*rowCnt,128) exit immediately.
// ---------------------------------------------------------------------------
template <bool RELU>
__global__ __launch_bounds__(256) void sgemm_bias(
    const float* __restrict__ A, const float* __restrict__ B,
    const float* __restrict__ bias, float* __restrict__ C,
    int M, int Nn, int Kk, int lda, int ldb, int ldc,
    const uint32_t* __restrict__ rowCnt) {
  const int BM = 128, BN = 128, BK = 16;
  __shared__ float As[BK][BM + 4];
  __shared__ float Bs[BK][BN + 8];

  int tid = threadIdx.x;
  int bm = blockIdx.x, bn = blockIdx.y;

  if (rowCnt) {
    int cc = (int)*rowCnt;
    if (cc > CAND_CAP) cc = CAND_CAP;
    int padded = (cc + 127) & ~127;
    if (bm * BM >= padded) return;  // uniform per block: safe early exit
  }

  int tx = tid & 15, ty = tid >> 4;
  int a_k2 = tid & 7;
  int a_m = tid >> 3;
  int b_c4 = tid & 31;
  int b_kr = tid >> 5;

  const float* aPtr = A + (size_t)(bm * BM + a_m) * lda + a_k2 * 2;
  const float* bPtr = B + (size_t)b_kr * ldb + (size_t)bn * BN + b_c4 * 4;

  float acc[8][8];
#pragma unroll
  for (int i = 0; i < 8; ++i)
#pragma unroll
    for (int j = 0; j < 8; ++j) acc[i][j] = 0.f;

  for (int k0 = 0; k0 < Kk; k0 += BK) {
#pragma unroll
    for (int p = 0; p < 4; ++p) {
      float2 v = *(const float2*)(aPtr + (size_t)p * 32 * lda);
      As[a_k2 * 2 + 0][a_m + p * 32] = v.x;
      As[a_k2 * 2 + 1][a_m + p * 32] = v.y;
    }
#pragma unroll
    for (int p = 0; p < 2; ++p) {
      float4 v = *(const float4*)(bPtr + (size_t)p * 8 * ldb);
      *(float4*)&Bs[b_kr + p * 8][b_c4 * 4] = v;
    }
    aPtr += BK;
    bPtr += (size_t)BK * ldb;
    __syncthreads();

#pragma unroll
    for (int kk = 0; kk < BK; ++kk) {
      float4 a0 = *(const float4*)&As[kk][ty * 8];
      float4 a1 = *(const float4*)&As[kk][ty * 8 + 4];
      float4 b0 = *(const float4*)&Bs[kk][tx * 8];
      float4 b1 = *(const float4*)&Bs[kk][tx * 8 + 4];
#pragma unroll
      for (int i = 0; i < 8; ++i) {
        float ai = (i < 4) ? ((i == 0) ? a0.x : (i == 1) ? a0.y : (i == 2) ? a0.z : a0.w)
                           : ((i == 4) ? a1.x : (i == 5) ? a1.y : (i == 6) ? a1.z : a1.w);
        acc[i][0] = fmaf(ai, b0.x, acc[i][0]);
        acc[i][1] = fmaf(ai, b0.y, acc[i][1]);
        acc[i][2] = fmaf(ai, b0.z, acc[i][2]);
        acc[i][3] = fmaf(ai, b0.w, acc[i][3]);
        acc[i][4] = fmaf(ai, b1.x, acc[i][4]);
        acc[i][5] = fmaf(ai, b1.y, acc[i][5]);
        acc[i][6] = fmaf(ai, b1.z, acc[i][6]);
        acc[i][7] = fmaf(ai, b1.w, acc[i][7]);
      }
    }
    __syncthreads();
  }

  int col0 = bn * BN + tx * 8;
  float bb[8];
#pragma unroll
  for (int j = 0; j < 8; ++j) bb[j] = bias[col0 + j];
#pragma unroll
  for (int i = 0; i < 8; ++i) {
    int row = bm * BM + ty * 8 + i;
    float o[8];
#pragma unroll
    for (int j = 0; j < 8; ++j) {
      float v = acc[i][j] + bb[j];
      o[j] = RELU ? fmaxf(v, 0.f) : v;
    }
    *(float4*)(C + (size_t)row * ldc + col0) = make_float4(o[0], o[1], o[2], o[3]);
    *(float4*)(C + (size_t)row * ldc + col0 + 4) = make_float4(o[4], o[5], o[6], o[7]);
  }
}

// ---------------------------------------------------------------------------
// bf16 MFMA GEMM: Out_bf16 = relu(A_bf16 @ B_bf16 + bias). 16x16x32 MFMA.
// Block 256 thr = 4 waves (2x2), tile 128x64, BK=32. N fixed 512, M = 320*128.
// Swizzle: xcd=w&7, s=w>>3, p=(s>>3)<<3|xcd, bn=s&7 -> the 8 bn-blocks of a
// row-panel are CONSECUTIVE in each XCD's dispatch order (co-resident), so
// the per-XCD L2 working set is ~1 bf16 A-panel (384 KB) + B (<=1.5 MiB).
// Frag layouts (16x16x32): A row=l&15, k=(l>>4)*8+j ; B col=l&15, same k;
// C/D col=l&15, row=(l>>4)*4+r  [guide m89; validated end-to-end in R4].
// ---------------------------------------------------------------------------
__global__ __launch_bounds__(256) void mfma_gemm(
    const ushort* __restrict__ Ab, const ushort* __restrict__ Bb,
    const float* __restrict__ bias, ushort* __restrict__ Out,
    int K, int lda) {
  __shared__ ushort As[128][48];
  __shared__ ushort Bs[64][48];   // transposed: Bs[n][k]

  int wgl = blockIdx.x;
  int xcd = wgl & 7;
  int s = wgl >> 3;
  int p = ((s >> 3) << 3) | xcd;  // row panel, slow within XCD
  int bn = s & 7;                 // col block, fast within XCD
  int tid = threadIdx.x;
  int w = tid >> 6, l = tid & 63;
  int waveM = w & 1, waveN = w >> 1;
  int lr = l & 15, lg = l >> 4;
  int rowbase = p * 128;

  f32x4 acc[4][2];
#pragma unroll
  for (int m = 0; m < 4; ++m)
#pragma unroll
    for (int n = 0; n < 2; ++n)
#pragma unroll
      for (int r = 0; r < 4; ++r) acc[m][n][r] = 0.f;

  for (int k0 = 0; k0 < K; k0 += 32) {
    // stage A tile 128x32 (bf16, 16B vector copies)
#pragma unroll
    for (int it = 0; it < 2; ++it) {
      int idx = tid + it * 256;  // 0..511
      int ar = idx >> 2;
      int kc = (idx & 3) * 8;
      const ushort* src = Ab + (size_t)(rowbase + ar) * lda + k0 + kc;
      *(uint4*)&As[ar][kc] = *(const uint4*)src;
    }
    // stage B tile 32x64, transposed into Bs[n][k]
    {
      int n = tid & 63;
      int kk0 = (tid >> 6) * 8;
#pragma unroll
      for (int i = 0; i < 8; ++i)
        Bs[n][kk0 + i] = Bb[(size_t)(k0 + kk0 + i) * 512 + bn * 64 + n];
    }
    __syncthreads();

    bf16x8 af[4], bv[2];
#pragma unroll
    for (int m = 0; m < 4; ++m)
      af[m] = *(const bf16x8*)&As[waveM * 64 + m * 16 + lr][lg * 8];
#pragma unroll
    for (int n = 0; n < 2; ++n)
      bv[n] = *(const bf16x8*)&Bs[waveN * 32 + n * 16 + lr][lg * 8];
#pragma unroll
    for (int m = 0; m < 4; ++m)
#pragma unroll
      for (int n = 0; n < 2; ++n)
        acc[m][n] = __builtin_amdgcn_mfma_f32_16x16x32_bf16(af[m], bv[n], acc[m][n], 0, 0, 0);
    __syncthreads();
  }

#pragma unroll
  for (int m = 0; m < 4; ++m) {
    int rg = rowbase + waveM * 64 + m * 16 + lg * 4;
#pragma unroll
    for (int n = 0; n < 2; ++n) {
      int cg = bn * 64 + waveN * 32 + n * 16 + lr;
      float bb = bias[cg];
#pragma unroll
      for (int r = 0; r < 4; ++r) {
        float v = fmaxf(acc[m][n][r] + bb, 0.f);
        Out[(size_t)(rg + r) * 512 + cg] = f2bf(v);
      }
    }
  }
}

// ---------------------------------------------------------------------------
__global__ void cvt_bf16_kernel(const float* __restrict__ src, ushort* __restrict__ dst, int n) {
  int i = blockIdx.x * blockDim.x + threadIdx.x;
  if (i < n) dst[i] = f2bf(src[i]);
}

// Row dot fp32: out[r] = dot(X[r,0:512], w) + b[0]. One wave per row.
// cnt != null: rows >= min(*cnt, CAND_CAP) skipped (outputs unread).
__global__ __launch_bounds__(256) void rowdot_kernel(
    const float* __restrict__ X, const float* __restrict__ w,
    const float* __restrict__ b, float* __restrict__ out, int rows,
    const uint32_t* __restrict__ cnt) {
  int gid = blockIdx.x * blockDim.x + threadIdx.x;
  int wave = gid >> 6;
  int lane = threadIdx.x & 63;
  if (wave >= rows) return;
  if (cnt) {
    int cc = (int)*cnt;
    if (cc > CAND_CAP) cc = CAND_CAP;
    if (wave >= cc) return;
  }
  const float* x = X + (size_t)wave * H_DIM;
  float s = 0.f;
#pragma unroll
  for (int i = 0; i < 8; ++i) s = fmaf(x[lane + i * 64], w[lane + i * 64], s);
#pragma unroll
  for (int off = 32; off > 0; off >>= 1) s += __shfl_down(s, off);
  if (lane == 0) out[wave] = s + b[0];
}

// Row dot bf16 input (approx path).
__global__ __launch_bounds__(256) void rowdot_bf16_kernel(
    const ushort* __restrict__ X, const float* __restrict__ w,
    const float* __restrict__ b, float* __restrict__ out, int rows) {
  int gid = blockIdx.x * blockDim.x + threadIdx.x;
  int wave = gid >> 6;
  int lane = threadIdx.x & 63;
  if (wave >= rows) return;
  const ushort* x = X + (size_t)wave * H_DIM;
  float s = 0.f;
#pragma unroll
  for (int i = 0; i < 8; ++i) s = fmaf(bf2f(x[lane + i * 64]), w[lane + i * 64], s);
#pragma unroll
  for (int off = 32; off > 0; off >>= 1) s += __shfl_down(s, off);
  if (lane == 0) out[wave] = s + b[0];
}

// ---------------------------------------------------------------------------
// Span kernel (fp32 path bit-matches R2/R4-validated). Also emits g_bf
// (RNE bf16 copy) so mfma1 reads bf16 A — values bit-identical to R4's
// in-staging conversion, so the approx path is unchanged.
// ---------------------------------------------------------------------------
__global__ __launch_bounds__(256) void span_kernel(
    const float* __restrict__ states, const float* __restrict__ embeds,
    const int* __restrict__ starts, const int* __restrict__ widths,
    const float* __restrict__ attns, float* __restrict__ g,
    ushort* __restrict__ g_bf) {
  int n = blockIdx.x;
  int tid = threadIdx.x;
  int st = starts[n];
  int wd = widths[n];

  float w[L_SPAN];
  float mx = -1e30f;
#pragma unroll
  for (int l = 0; l < L_SPAN; ++l) {
    float a = attns[st + l];  // in-range: st+9 <= T-1
    a = (l <= wd) ? a : -1e30f;
    w[l] = a;
    mx = fmaxf(mx, a);
  }
  float ssum = 0.f;
#pragma unroll
  for (int l = 0; l < L_SPAN; ++l) {
    float e = expf(w[l] - mx);
    e = (l <= wd) ? e : 0.f;
    w[l] = e;
    ssum += e;
  }
  float inv = 1.f / ssum;

  int d = tid * 2;
  float2 att = make_float2(0.f, 0.f);
#pragma unroll
  for (int l = 0; l < L_SPAN; ++l) {
    float2 e = *(const float2*)(embeds + (size_t)(st + l) * D_DIM + d);
    float wl = w[l] * inv;
    att.x = fmaf(wl, e.x, att.x);
    att.y = fmaf(wl, e.y, att.y);
  }

  float* grow = g + (size_t)n * (3 * D_DIM);
  float2 s0 = *(const float2*)(states + (size_t)st * D_DIM + d);
  float2 s1 = *(const float2*)(states + (size_t)(st + wd) * D_DIM + d);
  *(float2*)(grow + d) = s0;
  *(float2*)(grow + D_DIM + d) = s1;
  *(float2*)(grow + 2 * D_DIM + d) = att;

  ushort* brow = g_bf + (size_t)n * (3 * D_DIM);
  ushort2 b0 = make_ushort2(f2bf(s0.x), f2bf(s0.y));
  ushort2 b1 = make_ushort2(f2bf(s1.x), f2bf(s1.y));
  ushort2 b2 = make_ushort2(f2bf(att.x), f2bf(att.y));
  *(ushort2*)(brow + d) = b0;
  *(ushort2*)(brow + D_DIM + d) = b1;
  *(ushort2*)(brow + 2 * D_DIM + d) = b2;
}

// ---------------------------------------------------------------------------
// Radix-select machinery on approx scores.
// meta: 0:b1 1:rem1 2:thr_key 3:need_eq 6:candCount
// ---------------------------------------------------------------------------
__global__ void keys_kernel(const float* __restrict__ scores, uint32_t* __restrict__ keys) {
  int n = blockIdx.x * blockDim.x + threadIdx.x;
  if (n < N_SPAN) {
    uint32_t u = __float_as_uint(scores[n]);
    keys[n] = (u & 0x80000000u) ? ~u : (u | 0x80000000u);
  }
}

__global__ void zero_kernel(uint32_t* __restrict__ p, int n) {
  int i = blockIdx.x * blockDim.x + threadIdx.x;
  if (i < n) p[i] = 0u;
}

__global__ void hist_hi_kernel(const uint32_t* __restrict__ keys, uint32_t* __restrict__ hist) {
  int n = blockIdx.x * blockDim.x + threadIdx.x;
  if (n < N_SPAN) atomicAdd(&hist[keys[n] >> 16], 1u);
}

__global__ void hist_lo_kernel(const uint32_t* __restrict__ keys,
                               const uint32_t* __restrict__ meta,
                               uint32_t* __restrict__ hist) {
  int n = blockIdx.x * blockDim.x + threadIdx.x;
  if (n < N_SPAN) {
    uint32_t k = keys[n];
    if ((k >> 16) == meta[0]) atomicAdd(&hist[k & 0xffffu], 1u);
  }
}

__global__ __launch_bounds__(1024) void select_kernel(
    const uint32_t* __restrict__ hist, uint32_t* __restrict__ meta, int level) {
  __shared__ uint32_t csum[1024];
  int tid = threadIdx.x;
  uint32_t Kwant = (level == 0) ? (uint32_t)K_TOP : meta[1];

  uint32_t s = 0;
  for (int j = 0; j < 64; ++j) s += hist[tid * 64 + j];
  csum[tid] = s;
  __syncthreads();
  for (int off = 1; off < 1024; off <<= 1) {
    uint32_t other = (tid + off < 1024) ? csum[tid + off] : 0u;
    __syncthreads();
    csum[tid] += other;
    __syncthreads();
  }
  if (csum[tid] >= Kwant && (tid == 1023 || csum[tid + 1] < Kwant)) {
    uint32_t running = (tid == 1023) ? 0u : csum[tid + 1];
    for (int j = 63; j >= 0; --j) {
      uint32_t h = hist[tid * 64 + j];
      if (running + h >= Kwant) {
        if (level == 0) {
          meta[0] = (uint32_t)(tid * 64 + j);
          meta[1] = Kwant - running;
        } else {
          meta[2] = (meta[0] << 16) | (uint32_t)(tid * 64 + j);
          meta[3] = Kwant - running;
        }
        break;
      }
      running += h;
    }
  }
}

// Candidates: approx key >= key(float(thr) - MARGIN).
__global__ void compact_cand(const uint32_t* __restrict__ keys, uint32_t* __restrict__ meta,
                             int* __restrict__ candIdx) {
  int n = blockIdx.x * blockDim.x + threadIdx.x;
  if (n >= N_SPAN) return;
  uint32_t tk = meta[2];
  uint32_t tu = (tk & 0x80000000u) ? (tk & 0x7FFFFFFFu) : ~tk;  // inverse key->bits
  float tf = __uint_as_float(tu) - MARGIN;
  uint32_t mu = __float_as_uint(tf);
  uint32_t mk = (mu & 0x80000000u) ? ~mu : (mu | 0x80000000u);
  if (keys[n] >= mk) {
    uint32_t p = atomicAdd(&meta[6], 1u);
    if (p < CAND_CAP) candIdx[p] = n;
  }
}

// Gather candidate g rows -> cand_g [CAND_CAP x 1536], zero-padded.
__global__ __launch_bounds__(256) void gather_kernel(
    const float* __restrict__ g, const uint32_t* __restrict__ meta,
    const int* __restrict__ candIdx, float* __restrict__ cand_g) {
  int r = blockIdx.x;
  int C = (int)meta[6];
  if (C > CAND_CAP) C = CAND_CAP;
  bool valid = r < C;
  int idx = valid ? candIdx[r] : 0;
  const float* srow = g + (size_t)idx * (3 * D_DIM);
  float* drow = cand_g + (size_t)r * (3 * D_DIM);
  for (int i = threadIdx.x; i < 768; i += 256) {
    float2 v = valid ? *(const float2*)(srow + i * 2) : make_float2(0.f, 0.f);
    *(float2*)(drow + i * 2) = v;
  }
}

// ---------------------------------------------------------------------------
// Final: among candidates (exact fp32 scores), top-K_TOP with stable
// tie-break (lowest index first), then sort selected by index. One block.
// ---------------------------------------------------------------------------
__global__ __launch_bounds__(1024) void final_hybrid(
    const uint32_t* __restrict__ meta, const int* __restrict__ candIdx,
    const float* __restrict__ candExact,
    float* __restrict__ out_scores, float* __restrict__ out_idx) {
  __shared__ uint64_t pr[8192];  // 64 KB
  int tid = threadIdx.x;
  int C = (int)meta[6];
  if (C > CAND_CAP) C = CAND_CAP;

  for (int i = tid; i < 8192; i += 1024) {
    uint64_t inv = ~0ULL;  // pad sorts last
    if (i < C) {
      uint32_t u = __float_as_uint(candExact[i]);
      uint32_t k = (u & 0x80000000u) ? ~u : (u | 0x80000000u);
      uint32_t orig = (uint32_t)candIdx[i];
      uint32_t low = ((0xFFFFu - orig) << 13) | (uint32_t)i;
      inv = ~(((uint64_t)k << 32) | low);
    }
    pr[i] = inv;
  }
  __syncthreads();
  for (int kk = 2; kk <= 8192; kk <<= 1) {
    for (int j = kk >> 1; j > 0; j >>= 1) {
      for (int t = tid; t < 8192; t += 1024) {
        int ixj = t ^ j;
        if (ixj > t) {
          bool up = ((t & kk) == 0);
          uint64_t a = pr[t], b = pr[ixj];
          if ((a > b) == up) { pr[t] = b; pr[ixj] = a; }
        }
      }
      __syncthreads();
    }
  }
  uint64_t mine[2];
#pragma unroll
  for (int t = 0; t < 2; ++t) {
    int i = tid + t * 1024;
    uint64_t v = ~pr[i];
    uint32_t low = (uint32_t)v;
    uint32_t orig = 0xFFFFu - ((low >> 13) & 0xFFFFu);
    uint32_t slot = low & 0x1FFFu;
    mine[t] = (i < K_TOP) ? (((uint64_t)orig << 32) | slot) : ~0ULL;
  }
  __syncthreads();
  pr[tid] = mine[0];
  pr[tid + 1024] = mine[1];
  __syncthreads();
  for (int kk = 2; kk <= 2048; kk <<= 1) {
    for (int j = kk >> 1; j > 0; j >>= 1) {
      for (int t = tid; t < 2048; t += 1024) {
        int ixj = t ^ j;
        if (ixj > t) {
          bool up = ((t & kk) == 0);
          uint64_t a = pr[t], b = pr[ixj];
          if ((a > b) == up) { pr[t] = b; pr[ixj] = a; }
        }
      }
      __syncthreads();
    }
  }
  for (int i = tid; i < K_TOP; i += 1024) {
    uint64_t v = pr[i];
    out_idx[i] = (float)(uint32_t)(v >> 32);
    out_scores[i] = candExact[v & 0x1FFFu];
  }
}

// ---------------------------------------------------------------------------
extern "C" void kernel_launch(void* const* d_in, const int* in_sizes, int n_in,
                              void* d_out, int out_size, void* d_ws, size_t ws_size,
                              hipStream_t stream) {
  const float* states = (const float*)d_in[0];
  const float* embeds = (const float*)d_in[1];
  const int* starts = (const int*)d_in[2];
  const int* widths = (const int*)d_in[3];
  const float* W_a1 = (const float*)d_in[4];
  const float* b_a1 = (const float*)d_in[5];
  const float* W_a2 = (const float*)d_in[6];
  const float* b_a2 = (const float*)d_in[7];
  const float* w_a3 = (const float*)d_in[8];
  const float* b_a3 = (const float*)d_in[9];
  const float* W_s1 = (const float*)d_in[10];
  const float* b_s1 = (const float*)d_in[11];
  const float* W_s2 = (const float*)d_in[12];
  const float* b_s2 = (const float*)d_in[13];
  const float* w_s3 = (const float*)d_in[14];
  const float* b_s3 = (const float*)d_in[15];

  float* out = (float*)d_out;
  float* out_scores = out;
  float* g = out + K_TOP;
  float* out_idx = out + K_TOP + (size_t)N_SPAN * 3 * D_DIM;

  // Workspace (MiB offsets; peak 162.5 MiB < 167 validated in R4).
  // Lifetime plan (R6: fixed the R5 overlap bug where s1b [0,40) clobbered
  // Wb1/Wb2/scoresA/keys/hist/candIdx at [17,23)):
  //   [0,120)   g_bf (span -> mfma1); after mfma1 dead ->
  //             s2b [0,40) | scoresA [40] | keys [41] | hist+meta [42] |
  //             candIdx [43] | cand_g [44,80) | e1 [80,92) | e2 [92,104) |
  //             candExact [104]
  //   [120,160) h1 [120,128) h2 [128,136) attns [136] (all dead pre-mfma1)
  //             -> s1b [120,160) (mfma1 out, mfma2 in)
  //   [160,163) Wb1 [160,161.5) Wb2 [162,162.5)  (live through mfma2)
  char* ws = (char*)d_ws;
  const size_t MB = 1024 * 1024;
  ushort* g_bf = (ushort*)(ws + 0);               // 120 MiB
  ushort* s2b = (ushort*)(ws + 0);                // 40 MiB (after g_bf dead)
  float* scoresA = (float*)(ws + 40 * MB);        // 160 KB
  uint32_t* keys = (uint32_t*)(ws + 41 * MB);     // 160 KB
  uint32_t* hist = (uint32_t*)(ws + 42 * MB);     // 256 KB
  uint32_t* meta = hist + 65536;                  // 16 u32
  int* candIdx = (int*)(ws + 43 * MB);            // 24 KB
  float* cand_g = (float*)(ws + 44 * MB);         // 36 MiB
  float* e1 = (float*)(ws + 80 * MB);             // 12 MiB
  float* e2 = (float*)(ws + 92 * MB);             // 12 MiB
  float* candExact = (float*)(ws + 104 * MB);     // 24 KB
  float* h1 = (float*)(ws + 120 * MB);            // 8 MiB
  float* h2 = (float*)(ws + 128 * MB);            // 8 MiB
  float* attns = (float*)(ws + 136 * MB);         // 16 KB
  ushort* s1b = (ushort*)(ws + 120 * MB);         // 40 MiB (after h1/h2/attns dead)
  ushort* Wb1 = (ushort*)(ws + 160 * MB);         // 1.5 MiB
  ushort* Wb2 = (ushort*)(ws + 162 * MB);         // 0.5 MiB

  // 0: weights -> bf16
  cvt_bf16_kernel<<<(3 * D_DIM * H_DIM) / 256, 256, 0, stream>>>(W_s1, Wb1, 3 * D_DIM * H_DIM);
  cvt_bf16_kernel<<<(H_DIM * H_DIM) / 256, 256, 0, stream>>>(W_s2, Wb2, H_DIM * H_DIM);

  // 1-3: attention MLP (fp32, bit-matches validated path)
  sgemm_bias<true><<<dim3(T_TOK / 128, H_DIM / 128), 256, 0, stream>>>(
      states, W_a1, b_a1, h1, T_TOK, H_DIM, D_DIM, D_DIM, H_DIM, H_DIM, nullptr);
  sgemm_bias<true><<<dim3(T_TOK / 128, H_DIM / 128), 256, 0, stream>>>(
      h1, W_a2, b_a2, h2, T_TOK, H_DIM, H_DIM, H_DIM, H_DIM, H_DIM, nullptr);
  rowdot_kernel<<<T_TOK / 4, 256, 0, stream>>>(h2, w_a3, b_a3, attns, T_TOK, nullptr);

  // 4: span softmax + g assembly (fp32 -> d_out) + g_bf (bf16 -> ws)
  span_kernel<<<N_SPAN, 256, 0, stream>>>(states, embeds, starts, widths, attns, g, g_bf);

  // 5-7: approx mention MLP via bf16 MFMA (bf16 A both layers)
  mfma_gemm<<<2560, 256, 0, stream>>>(g_bf, Wb1, b_s1, s1b, 3 * D_DIM, 3 * D_DIM);
  mfma_gemm<<<2560, 256, 0, stream>>>(s1b, Wb2, b_s2, s2b, H_DIM, H_DIM);
  rowdot_bf16_kernel<<<N_SPAN / 4, 256, 0, stream>>>(s2b, w_s3, b_s3, scoresA, N_SPAN);

  // 8: approx threshold via 2-level radix select
  keys_kernel<<<N_SPAN / 256, 256, 0, stream>>>(scoresA, keys);
  zero_kernel<<<(65536 + 16 + 255) / 256, 256, 0, stream>>>(hist, 65536 + 16);
  hist_hi_kernel<<<N_SPAN / 256, 256, 0, stream>>>(keys, hist);
  select_kernel<<<1, 1024, 0, stream>>>(hist, meta, 0);
  zero_kernel<<<65536 / 256, 256, 0, stream>>>(hist, 65536);
  hist_lo_kernel<<<N_SPAN / 256, 256, 0, stream>>>(keys, meta, hist);
  select_kernel<<<1, 1024, 0, stream>>>(hist, meta, 1);

  // 9-12: candidates -> exact fp32 re-score (bitwise = validated path),
  // with whole-tile early exit beyond the live candidate count.
  compact_cand<<<N_SPAN / 256, 256, 0, stream>>>(keys, meta, candIdx);
  gather_kernel<<<CAND_CAP, 256, 0, stream>>>(g, meta, candIdx, cand_g);
  sgemm_bias<true><<<dim3(CAND_CAP / 128, H_DIM / 128), 256, 0, stream>>>(
      cand_g, W_s1, b_s1, e1, CAND_CAP, H_DIM, 3 * D_DIM, 3 * D_DIM, H_DIM, H_DIM, meta + 6);
  sgemm_bias<true><<<dim3(CAND_CAP / 128, H_DIM / 128), 256, 0, stream>>>(
      e1, W_s2, b_s2, e2, CAND_CAP, H_DIM, H_DIM, H_DIM, H_DIM, H_DIM, meta + 6);
  rowdot_kernel<<<CAND_CAP / 4, 256, 0, stream>>>(e2, w_s3, b_s3, candExact, CAND_CAP, meta + 6);

  // 13: exact top-K among candidates + index sort + output
  final_hybrid<<<1, 1024, 0, stream>>>(meta, candIdx, candExact, out_scores, out_idx);
}

// Round 8
// 991.516 us; speedup vs baseline: 15.7762x; 1.2654x over previous
//
#include <hip/hip_runtime.h>
#include <hip/hip_bf16.h>
#include <stdint.h>

// Problem constants (from reference)
#define T_TOK 4096
#define D_DIM 512
#define L_SPAN 10
#define H_DIM 512
#define N_SPAN 40960
#define K_TOP 1638      // int(0.4 * 4096)
#define CAND_CAP 6144   // candidate capacity for exact re-score
#define MARGIN 0.01f    // approx-score margin (bf16-path err ~0.002)

typedef __attribute__((ext_vector_type(8))) short bf16x8;
typedef __attribute__((ext_vector_type(4))) float f32x4;

__device__ __forceinline__ ushort f2bf(float x) {  // RNE float->bf16 bits
  uint32_t u = __float_as_uint(x);
  return (ushort)((u + 0x7FFFu + ((u >> 16) & 1u)) >> 16);
}
__device__ __forceinline__ float bf2f(ushort s) {
  return __uint_as_float(((uint32_t)s) << 16);
}

// ---------------------------------------------------------------------------
// fp32 GEMM, small-tile high-occupancy variant (R8). C = relu(A@B + bias).
// BM=32, BN=64, BK=32, 256 thr, 2x4 micro-tile -> ~13KB LDS, low VGPR,
// grid (N/64, M/32) = 1024-1536 blocks (vs 88-192 for the old 128-tile:
// occupancy 3.5%, VALUBusy 11% measured in R7 -> latency-bound).
// grid.x = col-tile: XCD c keeps B col-panel (<=384KB) L2-resident.
// Per-element accumulation is a single fmaf chain in ascending k ->
// BITWISE identical to the R2/R4-validated numeric path (tile shape only
// changes which block computes an element, not its summation order).
// INDEXED: A row r = A + rowIdx[r]*lda (candidate re-score, no gather);
// slots >= *rowCnt read row 0 (guard against poisoned rowIdx), outputs
// for those slots are never read downstream.
// ---------------------------------------------------------------------------
template <bool RELU, bool INDEXED>
__global__ __launch_bounds__(256) void sgemm32(
    const float* __restrict__ A, const float* __restrict__ B,
    const float* __restrict__ bias, float* __restrict__ C,
    int Kk, int lda, int ldb, int ldc,
    const uint32_t* __restrict__ rowCnt, const int* __restrict__ rowIdx) {
  const int BM = 32, BN = 64, BK = 32;
  __shared__ float As[BK][BM + 2];  // transposed As[k][m]; stride 34 (8B-aligned pairs)
  __shared__ float Bs[BK][BN + 4];  // Bs[k][n]; stride 68 (16B-aligned quads)

  int tid = threadIdx.x;
  int bn = blockIdx.x, bm = blockIdx.y;

  int cc = INDEXED ? 0 : 0x7fffffff;
  if (rowCnt) {
    cc = (int)*rowCnt;
    if (cc > CAND_CAP) cc = CAND_CAP;
    if (bm * BM >= ((cc + 31) & ~31)) return;  // uniform per block
  }

  int tx = tid & 15, ty = tid >> 4;   // micro-tile coords: col0=tx*4, row0=ty*2
  int a_m = tid >> 3;                 // 32 rows
  int a_k2 = tid & 7;                 // 8 float2 = 16 k per pass, 2 passes
  int b_c4 = tid & 15;                // 16 float4 = 64 cols
  int b_kr = tid >> 4;                // 16 k-rows per pass, 2 passes

  int slot = bm * BM + a_m;
  const float* aRow;
  if (INDEXED) {
    int grow = (slot < cc) ? rowIdx[slot] : 0;  // guard poisoned slots
    aRow = A + (size_t)grow * lda;
  } else {
    aRow = A + (size_t)slot * lda;
  }
  const float* bPtr = B + (size_t)b_kr * ldb + bn * BN + b_c4 * 4;

  float acc[2][4];
#pragma unroll
  for (int i = 0; i < 2; ++i)
#pragma unroll
    for (int j = 0; j < 4; ++j) acc[i][j] = 0.f;

  for (int k0 = 0; k0 < Kk; k0 += BK) {
    // stage A 32x32 (float2: g rows are only 8B-aligned), transposed
#pragma unroll
    for (int p = 0; p < 2; ++p) {
      float2 v = *(const float2*)(aRow + k0 + p * 16 + a_k2 * 2);
      As[p * 16 + a_k2 * 2 + 0][a_m] = v.x;
      As[p * 16 + a_k2 * 2 + 1][a_m] = v.y;
    }
    // stage B 32x64 (float4; weight rows 16B-aligned)
#pragma unroll
    for (int p = 0; p < 2; ++p) {
      float4 v = *(const float4*)(bPtr + (size_t)(k0 + p * 16) * ldb);
      *(float4*)&Bs[b_kr + p * 16][b_c4 * 4] = v;
    }
    __syncthreads();

#pragma unroll
    for (int kk = 0; kk < BK; ++kk) {
      float2 a = *(const float2*)&As[kk][ty * 2];
      float4 b = *(const float4*)&Bs[kk][tx * 4];
      acc[0][0] = fmaf(a.x, b.x, acc[0][0]);
      acc[0][1] = fmaf(a.x, b.y, acc[0][1]);
      acc[0][2] = fmaf(a.x, b.z, acc[0][2]);
      acc[0][3] = fmaf(a.x, b.w, acc[0][3]);
      acc[1][0] = fmaf(a.y, b.x, acc[1][0]);
      acc[1][1] = fmaf(a.y, b.y, acc[1][1]);
      acc[1][2] = fmaf(a.y, b.z, acc[1][2]);
      acc[1][3] = fmaf(a.y, b.w, acc[1][3]);
    }
    __syncthreads();
  }

  int col0 = bn * BN + tx * 4;
  float4 bb = *(const float4*)(bias + col0);
#pragma unroll
  for (int i = 0; i < 2; ++i) {
    int row = bm * BM + ty * 2 + i;
    float o0 = acc[i][0] + bb.x;
    float o1 = acc[i][1] + bb.y;
    float o2 = acc[i][2] + bb.z;
    float o3 = acc[i][3] + bb.w;
    if (RELU) {
      o0 = fmaxf(o0, 0.f); o1 = fmaxf(o1, 0.f);
      o2 = fmaxf(o2, 0.f); o3 = fmaxf(o3, 0.f);
    }
    *(float4*)(C + (size_t)row * ldc + col0) = make_float4(o0, o1, o2, o3);
  }
}

// ---------------------------------------------------------------------------
// bf16 MFMA GEMM: Out_bf16 = relu(A_bf16 @ B_bf16 + bias). 16x16x32 MFMA.
// Block 256 thr = 4 waves (2x2), tile 128x64, BK=32. N fixed 512, M = 320*128.
// Swizzle: xcd=w&7, s=w>>3, p=(s>>3)<<3|xcd, bn=s&7 -> the 8 bn-blocks of a
// row-panel are CONSECUTIVE in each XCD's dispatch order (co-resident).
// Validated end-to-end in R4/R7; untouched in R8 (measured-first discipline).
// ---------------------------------------------------------------------------
__global__ __launch_bounds__(256) void mfma_gemm(
    const ushort* __restrict__ Ab, const ushort* __restrict__ Bb,
    const float* __restrict__ bias, ushort* __restrict__ Out,
    int K, int lda) {
  __shared__ ushort As[128][48];
  __shared__ ushort Bs[64][48];   // transposed: Bs[n][k]

  int wgl = blockIdx.x;
  int xcd = wgl & 7;
  int s = wgl >> 3;
  int p = ((s >> 3) << 3) | xcd;  // row panel, slow within XCD
  int bn = s & 7;                 // col block, fast within XCD
  int tid = threadIdx.x;
  int w = tid >> 6, l = tid & 63;
  int waveM = w & 1, waveN = w >> 1;
  int lr = l & 15, lg = l >> 4;
  int rowbase = p * 128;

  f32x4 acc[4][2];
#pragma unroll
  for (int m = 0; m < 4; ++m)
#pragma unroll
    for (int n = 0; n < 2; ++n)
#pragma unroll
      for (int r = 0; r < 4; ++r) acc[m][n][r] = 0.f;

  for (int k0 = 0; k0 < K; k0 += 32) {
#pragma unroll
    for (int it = 0; it < 2; ++it) {
      int idx = tid + it * 256;  // 0..511
      int ar = idx >> 2;
      int kc = (idx & 3) * 8;
      const ushort* src = Ab + (size_t)(rowbase + ar) * lda + k0 + kc;
      *(uint4*)&As[ar][kc] = *(const uint4*)src;
    }
    {
      int n = tid & 63;
      int kk0 = (tid >> 6) * 8;
#pragma unroll
      for (int i = 0; i < 8; ++i)
        Bs[n][kk0 + i] = Bb[(size_t)(k0 + kk0 + i) * 512 + bn * 64 + n];
    }
    __syncthreads();

    bf16x8 af[4], bv[2];
#pragma unroll
    for (int m = 0; m < 4; ++m)
      af[m] = *(const bf16x8*)&As[waveM * 64 + m * 16 + lr][lg * 8];
#pragma unroll
    for (int n = 0; n < 2; ++n)
      bv[n] = *(const bf16x8*)&Bs[waveN * 32 + n * 16 + lr][lg * 8];
#pragma unroll
    for (int m = 0; m < 4; ++m)
#pragma unroll
      for (int n = 0; n < 2; ++n)
        acc[m][n] = __builtin_amdgcn_mfma_f32_16x16x32_bf16(af[m], bv[n], acc[m][n], 0, 0, 0);
    __syncthreads();
  }

#pragma unroll
  for (int m = 0; m < 4; ++m) {
    int rg = rowbase + waveM * 64 + m * 16 + lg * 4;
#pragma unroll
    for (int n = 0; n < 2; ++n) {
      int cg = bn * 64 + waveN * 32 + n * 16 + lr;
      float bb = bias[cg];
#pragma unroll
      for (int r = 0; r < 4; ++r) {
        float v = fmaxf(acc[m][n][r] + bb, 0.f);
        Out[(size_t)(rg + r) * 512 + cg] = f2bf(v);
      }
    }
  }
}

// ---------------------------------------------------------------------------
__global__ void cvt_bf16_kernel(const float* __restrict__ src, ushort* __restrict__ dst, int n) {
  int i = blockIdx.x * blockDim.x + threadIdx.x;
  if (i < n) dst[i] = f2bf(src[i]);
}

// Row dot fp32: out[r] = dot(X[r,0:512], w) + b[0]. One wave per row.
// cnt != null: rows >= min(*cnt, CAND_CAP) skipped (outputs unread).
__global__ __launch_bounds__(256) void rowdot_kernel(
    const float* __restrict__ X, const float* __restrict__ w,
    const float* __restrict__ b, float* __restrict__ out, int rows,
    const uint32_t* __restrict__ cnt) {
  int gid = blockIdx.x * blockDim.x + threadIdx.x;
  int wave = gid >> 6;
  int lane = threadIdx.x & 63;
  if (wave >= rows) return;
  if (cnt) {
    int cc = (int)*cnt;
    if (cc > CAND_CAP) cc = CAND_CAP;
    if (wave >= cc) return;
  }
  const float* x = X + (size_t)wave * H_DIM;
  float s = 0.f;
#pragma unroll
  for (int i = 0; i < 8; ++i) s = fmaf(x[lane + i * 64], w[lane + i * 64], s);
#pragma unroll
  for (int off = 32; off > 0; off >>= 1) s += __shfl_down(s, off);
  if (lane == 0) out[wave] = s + b[0];
}

// Row dot bf16 input (approx path).
__global__ __launch_bounds__(256) void rowdot_bf16_kernel(
    const ushort* __restrict__ X, const float* __restrict__ w,
    const float* __restrict__ b, float* __restrict__ out, int rows) {
  int gid = blockIdx.x * blockDim.x + threadIdx.x;
  int wave = gid >> 6;
  int lane = threadIdx.x & 63;
  if (wave >= rows) return;
  const ushort* x = X + (size_t)wave * H_DIM;
  float s = 0.f;
#pragma unroll
  for (int i = 0; i < 8; ++i) s = fmaf(bf2f(x[lane + i * 64]), w[lane + i * 64], s);
#pragma unroll
  for (int off = 32; off > 0; off >>= 1) s += __shfl_down(s, off);
  if (lane == 0) out[wave] = s + b[0];
}

// ---------------------------------------------------------------------------
// Span kernel (fp32 path bit-matches R2/R4-validated). Also emits g_bf
// (RNE bf16) for the MFMA approx path — bit-identical to R4's staging cvt.
// ---------------------------------------------------------------------------
__global__ __launch_bounds__(256) void span_kernel(
    const float* __restrict__ states, const float* __restrict__ embeds,
    const int* __restrict__ starts, const int* __restrict__ widths,
    const float* __restrict__ attns, float* __restrict__ g,
    ushort* __restrict__ g_bf) {
  int n = blockIdx.x;
  int tid = threadIdx.x;
  int st = starts[n];
  int wd = widths[n];

  float w[L_SPAN];
  float mx = -1e30f;
#pragma unroll
  for (int l = 0; l < L_SPAN; ++l) {
    float a = attns[st + l];  // in-range: st+9 <= T-1
    a = (l <= wd) ? a : -1e30f;
    w[l] = a;
    mx = fmaxf(mx, a);
  }
  float ssum = 0.f;
#pragma unroll
  for (int l = 0; l < L_SPAN; ++l) {
    float e = expf(w[l] - mx);
    e = (l <= wd) ? e : 0.f;
    w[l] = e;
    ssum += e;
  }
  float inv = 1.f / ssum;

  int d = tid * 2;
  float2 att = make_float2(0.f, 0.f);
#pragma unroll
  for (int l = 0; l < L_SPAN; ++l) {
    float2 e = *(const float2*)(embeds + (size_t)(st + l) * D_DIM + d);
    float wl = w[l] * inv;
    att.x = fmaf(wl, e.x, att.x);
    att.y = fmaf(wl, e.y, att.y);
  }

  float* grow = g + (size_t)n * (3 * D_DIM);
  float2 s0 = *(const float2*)(states + (size_t)st * D_DIM + d);
  float2 s1 = *(const float2*)(states + (size_t)(st + wd) * D_DIM + d);
  *(float2*)(grow + d) = s0;
  *(float2*)(grow + D_DIM + d) = s1;
  *(float2*)(grow + 2 * D_DIM + d) = att;

  ushort* brow = g_bf + (size_t)n * (3 * D_DIM);
  ushort2 b0 = make_ushort2(f2bf(s0.x), f2bf(s0.y));
  ushort2 b1 = make_ushort2(f2bf(s1.x), f2bf(s1.y));
  ushort2 b2 = make_ushort2(f2bf(att.x), f2bf(att.y));
  *(ushort2*)(brow + d) = b0;
  *(ushort2*)(brow + D_DIM + d) = b1;
  *(ushort2*)(brow + 2 * D_DIM + d) = b2;
}

// ---------------------------------------------------------------------------
// Radix-select machinery on approx scores.
// meta: 0:b1 1:rem1 2:thr_key 3:need_eq 6:candCount
// ---------------------------------------------------------------------------
__global__ void keys_kernel(const float* __restrict__ scores, uint32_t* __restrict__ keys) {
  int n = blockIdx.x * blockDim.x + threadIdx.x;
  if (n < N_SPAN) {
    uint32_t u = __float_as_uint(scores[n]);
    keys[n] = (u & 0x80000000u) ? ~u : (u | 0x80000000u);
  }
}

__global__ void zero_kernel(uint32_t* __restrict__ p, int n) {
  int i = blockIdx.x * blockDim.x + threadIdx.x;
  if (i < n) p[i] = 0u;
}

__global__ void hist_hi_kernel(const uint32_t* __restrict__ keys, uint32_t* __restrict__ hist) {
  int n = blockIdx.x * blockDim.x + threadIdx.x;
  if (n < N_SPAN) atomicAdd(&hist[keys[n] >> 16], 1u);
}

__global__ void hist_lo_kernel(const uint32_t* __restrict__ keys,
                               const uint32_t* __restrict__ meta,
                               uint32_t* __restrict__ hist) {
  int n = blockIdx.x * blockDim.x + threadIdx.x;
  if (n < N_SPAN) {
    uint32_t k = keys[n];
    if ((k >> 16) == meta[0]) atomicAdd(&hist[k & 0xffffu], 1u);
  }
}

__global__ __launch_bounds__(1024) void select_kernel(
    const uint32_t* __restrict__ hist, uint32_t* __restrict__ meta, int level) {
  __shared__ uint32_t csum[1024];
  int tid = threadIdx.x;
  uint32_t Kwant = (level == 0) ? (uint32_t)K_TOP : meta[1];

  uint32_t s = 0;
  for (int j = 0; j < 64; ++j) s += hist[tid * 64 + j];
  csum[tid] = s;
  __syncthreads();
  for (int off = 1; off < 1024; off <<= 1) {
    uint32_t other = (tid + off < 1024) ? csum[tid + off] : 0u;
    __syncthreads();
    csum[tid] += other;
    __syncthreads();
  }
  if (csum[tid] >= Kwant && (tid == 1023 || csum[tid + 1] < Kwant)) {
    uint32_t running = (tid == 1023) ? 0u : csum[tid + 1];
    for (int j = 63; j >= 0; --j) {
      uint32_t h = hist[tid * 64 + j];
      if (running + h >= Kwant) {
        if (level == 0) {
          meta[0] = (uint32_t)(tid * 64 + j);
          meta[1] = Kwant - running;
        } else {
          meta[2] = (meta[0] << 16) | (uint32_t)(tid * 64 + j);
          meta[3] = Kwant - running;
        }
        break;
      }
      running += h;
    }
  }
}

// Candidates: approx key >= key(float(thr) - MARGIN).
__global__ void compact_cand(const uint32_t* __restrict__ keys, uint32_t* __restrict__ meta,
                             int* __restrict__ candIdx) {
  int n = blockIdx.x * blockDim.x + threadIdx.x;
  if (n >= N_SPAN) return;
  uint32_t tk = meta[2];
  uint32_t tu = (tk & 0x80000000u) ? (tk & 0x7FFFFFFFu) : ~tk;  // inverse key->bits
  float tf = __uint_as_float(tu) - MARGIN;
  uint32_t mu = __float_as_uint(tf);
  uint32_t mk = (mu & 0x80000000u) ? ~mu : (mu | 0x80000000u);
  if (keys[n] >= mk) {
    uint32_t p = atomicAdd(&meta[6], 1u);
    if (p < CAND_CAP) candIdx[p] = n;
  }
}

// ---------------------------------------------------------------------------
// Final: among candidates (exact fp32 scores), top-K_TOP with stable
// tie-break (lowest index first), then sort selected by index. One block.
// ---------------------------------------------------------------------------
__global__ __launch_bounds__(1024) void final_hybrid(
    const uint32_t* __restrict__ meta, const int* __restrict__ candIdx,
    const float* __restrict__ candExact,
    float* __restrict__ out_scores, float* __restrict__ out_idx) {
  __shared__ uint64_t pr[8192];  // 64 KB
  int tid = threadIdx.x;
  int C = (int)meta[6];
  if (C > CAND_CAP) C = CAND_CAP;

  for (int i = tid; i < 8192; i += 1024) {
    uint64_t inv = ~0ULL;  // pad sorts last
    if (i < C) {
      uint32_t u = __float_as_uint(candExact[i]);
      uint32_t k = (u & 0x80000000u) ? ~u : (u | 0x80000000u);
      uint32_t orig = (uint32_t)candIdx[i];
      uint32_t low = ((0xFFFFu - orig) << 13) | (uint32_t)i;
      inv = ~(((uint64_t)k << 32) | low);
    }
    pr[i] = inv;
  }
  __syncthreads();
  for (int kk = 2; kk <= 8192; kk <<= 1) {
    for (int j = kk >> 1; j > 0; j >>= 1) {
      for (int t = tid; t < 8192; t += 1024) {
        int ixj = t ^ j;
        if (ixj > t) {
          bool up = ((t & kk) == 0);
          uint64_t a = pr[t], b = pr[ixj];
          if ((a > b) == up) { pr[t] = b; pr[ixj] = a; }
        }
      }
      __syncthreads();
    }
  }
  uint64_t mine[2];
#pragma unroll
  for (int t = 0; t < 2; ++t) {
    int i = tid + t * 1024;
    uint64_t v = ~pr[i];
    uint32_t low = (uint32_t)v;
    uint32_t orig = 0xFFFFu - ((low >> 13) & 0xFFFFu);
    uint32_t slot = low & 0x1FFFu;
    mine[t] = (i < K_TOP) ? (((uint64_t)orig << 32) | slot) : ~0ULL;
  }
  __syncthreads();
  pr[tid] = mine[0];
  pr[tid + 1024] = mine[1];
  __syncthreads();
  for (int kk = 2; kk <= 2048; kk <<= 1) {
    for (int j = kk >> 1; j > 0; j >>= 1) {
      for (int t = tid; t < 2048; t += 1024) {
        int ixj = t ^ j;
        if (ixj > t) {
          bool up = ((t & kk) == 0);
          uint64_t a = pr[t], b = pr[ixj];
          if ((a > b) == up) { pr[t] = b; pr[ixj] = a; }
        }
      }
      __syncthreads();
    }
  }
  for (int i = tid; i < K_TOP; i += 1024) {
    uint64_t v = pr[i];
    out_idx[i] = (float)(uint32_t)(v >> 32);
    out_scores[i] = candExact[v & 0x1FFFu];
  }
}

// ---------------------------------------------------------------------------
extern "C" void kernel_launch(void* const* d_in, const int* in_sizes, int n_in,
                              void* d_out, int out_size, void* d_ws, size_t ws_size,
                              hipStream_t stream) {
  const float* states = (const float*)d_in[0];
  const float* embeds = (const float*)d_in[1];
  const int* starts = (const int*)d_in[2];
  const int* widths = (const int*)d_in[3];
  const float* W_a1 = (const float*)d_in[4];
  const float* b_a1 = (const float*)d_in[5];
  const float* W_a2 = (const float*)d_in[6];
  const float* b_a2 = (const float*)d_in[7];
  const float* w_a3 = (const float*)d_in[8];
  const float* b_a3 = (const float*)d_in[9];
  const float* W_s1 = (const float*)d_in[10];
  const float* b_s1 = (const float*)d_in[11];
  const float* W_s2 = (const float*)d_in[12];
  const float* b_s2 = (const float*)d_in[13];
  const float* w_s3 = (const float*)d_in[14];
  const float* b_s3 = (const float*)d_in[15];

  float* out = (float*)d_out;
  float* out_scores = out;
  float* g = out + K_TOP;
  float* out_idx = out + K_TOP + (size_t)N_SPAN * 3 * D_DIM;

  // Workspace (MiB offsets; peak 162.5 MiB, validated layout from R7;
  // cand_g region [44,80) now unused after the indexed-A rescore).
  char* ws = (char*)d_ws;
  const size_t MB = 1024 * 1024;
  ushort* g_bf = (ushort*)(ws + 0);               // 120 MiB
  ushort* s2b = (ushort*)(ws + 0);                // 40 MiB (after g_bf dead)
  float* scoresA = (float*)(ws + 40 * MB);        // 160 KB
  uint32_t* keys = (uint32_t*)(ws + 41 * MB);     // 160 KB
  uint32_t* hist = (uint32_t*)(ws + 42 * MB);     // 256 KB
  uint32_t* meta = hist + 65536;                  // 16 u32
  int* candIdx = (int*)(ws + 43 * MB);            // 24 KB
  float* e1 = (float*)(ws + 80 * MB);             // 12 MiB
  float* e2 = (float*)(ws + 92 * MB);             // 12 MiB
  float* candExact = (float*)(ws + 104 * MB);     // 24 KB
  float* h1 = (float*)(ws + 120 * MB);            // 8 MiB
  float* h2 = (float*)(ws + 128 * MB);            // 8 MiB
  float* attns = (float*)(ws + 136 * MB);         // 16 KB
  ushort* s1b = (ushort*)(ws + 120 * MB);         // 40 MiB (after h1/h2/attns dead)
  ushort* Wb1 = (ushort*)(ws + 160 * MB);         // 1.5 MiB
  ushort* Wb2 = (ushort*)(ws + 162 * MB);         // 0.5 MiB

  // 0: weights -> bf16
  cvt_bf16_kernel<<<(3 * D_DIM * H_DIM) / 256, 256, 0, stream>>>(W_s1, Wb1, 3 * D_DIM * H_DIM);
  cvt_bf16_kernel<<<(H_DIM * H_DIM) / 256, 256, 0, stream>>>(W_s2, Wb2, H_DIM * H_DIM);

  // 1-3: attention MLP (fp32, bitwise = validated chain; 32x64 tiles)
  sgemm32<true, false><<<dim3(H_DIM / 64, T_TOK / 32), 256, 0, stream>>>(
      states, W_a1, b_a1, h1, D_DIM, D_DIM, H_DIM, H_DIM, nullptr, nullptr);
  sgemm32<true, false><<<dim3(H_DIM / 64, T_TOK / 32), 256, 0, stream>>>(
      h1, W_a2, b_a2, h2, H_DIM, H_DIM, H_DIM, H_DIM, nullptr, nullptr);
  rowdot_kernel<<<T_TOK / 4, 256, 0, stream>>>(h2, w_a3, b_a3, attns, T_TOK, nullptr);

  // 4: span softmax + g assembly (fp32 -> d_out) + g_bf (bf16 -> ws)
  span_kernel<<<N_SPAN, 256, 0, stream>>>(states, embeds, starts, widths, attns, g, g_bf);

  // 5-7: approx mention MLP via bf16 MFMA (bf16 A both layers)
  mfma_gemm<<<2560, 256, 0, stream>>>(g_bf, Wb1, b_s1, s1b, 3 * D_DIM, 3 * D_DIM);
  mfma_gemm<<<2560, 256, 0, stream>>>(s1b, Wb2, b_s2, s2b, H_DIM, H_DIM);
  rowdot_bf16_kernel<<<N_SPAN / 4, 256, 0, stream>>>(s2b, w_s3, b_s3, scoresA, N_SPAN);

  // 8: approx threshold via 2-level radix select
  keys_kernel<<<N_SPAN / 256, 256, 0, stream>>>(scoresA, keys);
  zero_kernel<<<(65536 + 16 + 255) / 256, 256, 0, stream>>>(hist, 65536 + 16);
  hist_hi_kernel<<<N_SPAN / 256, 256, 0, stream>>>(keys, hist);
  select_kernel<<<1, 1024, 0, stream>>>(hist, meta, 0);
  zero_kernel<<<65536 / 256, 256, 0, stream>>>(hist, 65536);
  hist_lo_kernel<<<N_SPAN / 256, 256, 0, stream>>>(keys, meta, hist);
  select_kernel<<<1, 1024, 0, stream>>>(hist, meta, 1);

  // 9-11: candidates -> exact fp32 re-score (bitwise = validated chain),
  // indexed-A (no gather), whole-tile early exit beyond candidate count.
  compact_cand<<<N_SPAN / 256, 256, 0, stream>>>(keys, meta, candIdx);
  sgemm32<true, true><<<dim3(H_DIM / 64, CAND_CAP / 32), 256, 0, stream>>>(
      g, W_s1, b_s1, e1, 3 * D_DIM, 3 * D_DIM, H_DIM, H_DIM, meta + 6, candIdx);
  sgemm32<true, false><<<dim3(H_DIM / 64, CAND_CAP / 32), 256, 0, stream>>>(
      e1, W_s2, b_s2, e2, H_DIM, H_DIM, H_DIM, H_DIM, meta + 6, nullptr);
  rowdot_kernel<<<CAND_CAP / 4, 256, 0, stream>>>(e2, w_s3, b_s3, candExact, CAND_CAP, meta + 6);

  // 12: exact top-K among candidates + index sort + output
  final_hybrid<<<1, 1024, 0, stream>>>(meta, candIdx, candExact, out_scores, out_idx);
}